// Round 5
// baseline (1165.939 us; speedup 1.0000x reference)
//
#include <hip/hip_runtime.h>

// Problem constants (match reference)
#define G_  4
#define N_  100000
#define E_  500000
#define B_  512
#define V_  50000
#define D_  300
#define H_  128
#define C_  20
#define NH_ 3

#define SCB_  512                       // elems per scan block
#define NBLK_ ((N_ + SCB_ - 1) / SCB_)  // 196

__device__ __forceinline__ int lower_bound_i(const int* __restrict__ a, int n, int v) {
    int lo = 0, hi = n;
    while (lo < hi) {
        int mid = (lo + hi) >> 1;
        if (a[mid] < v) lo = mid + 1; else hi = mid;
    }
    return lo;
}

// ---------------------------------------------------------------------------
// Table projection GEMM: P[g][v][h] = sum_k emb[v][k] * Wp[g][k][h] + bp[g][h]
// grid = (ng, V/128): blockIdx.x = graph so blocks sharing an A-tile dispatch
// adjacently (L2/L3 A reuse). BM=128, BN=128, BK=16, 8x8/thread.
// ---------------------------------------------------------------------------
__global__ __launch_bounds__(256) void table_gemm_kernel(
    const float* __restrict__ A,    // emb_table [V][300]
    const float* __restrict__ Wp,   // [ng][300][128]
    const float* __restrict__ bp,   // [ng][128]
    float* __restrict__ P)          // [ng][V][128]
{
    __shared__ __align__(16) float As[16][128 + 4];  // As[k][m]
    __shared__ __align__(16) float Bs[16][128 + 4];  // Bs[k][n]

    const int t    = threadIdx.x;
    const int g    = blockIdx.x;
    const int row0 = blockIdx.y * 128;

    const float* Bg = Wp + (size_t)g * D_ * H_;
    float*       Pg = P  + (size_t)g * V_ * H_;

    const int ty = t >> 4;   // 0..15
    const int tx = t & 15;   // 0..15

    float acc[8][8];
#pragma unroll
    for (int i = 0; i < 8; ++i)
#pragma unroll
        for (int j = 0; j < 8; ++j) acc[i][j] = 0.f;

    for (int k0 = 0; k0 < 304; k0 += 16) {
        // --- load A tile (transposed into LDS) ---
#pragma unroll
        for (int i = 0; i < 2; ++i) {
            int flat = t + i * 256;
            int m  = flat >> 2;        // 0..127
            int kq = flat & 3;         // 0..3
            int row = row0 + m;
            int k   = k0 + kq * 4;
            float4 v = make_float4(0.f, 0.f, 0.f, 0.f);
            if (row < V_ && k <= D_ - 4)
                v = *reinterpret_cast<const float4*>(&A[(size_t)row * D_ + k]);
            As[kq * 4 + 0][m] = v.x;
            As[kq * 4 + 1][m] = v.y;
            As[kq * 4 + 2][m] = v.z;
            As[kq * 4 + 3][m] = v.w;
        }
        // --- load B tile ---
#pragma unroll
        for (int i = 0; i < 2; ++i) {
            int flat = t + i * 256;
            int k  = flat >> 5;        // 0..15
            int nq = flat & 31;        // 0..31
            float4 v = make_float4(0.f, 0.f, 0.f, 0.f);
            if (k0 + k < D_)
                v = *reinterpret_cast<const float4*>(&Bg[(size_t)(k0 + k) * H_ + nq * 4]);
            *reinterpret_cast<float4*>(&Bs[k][nq * 4]) = v;
        }
        __syncthreads();

#pragma unroll
        for (int k = 0; k < 16; ++k) {
            float4 a0 = *reinterpret_cast<const float4*>(&As[k][ty * 4]);
            float4 a1 = *reinterpret_cast<const float4*>(&As[k][ty * 4 + 64]);
            float4 b0 = *reinterpret_cast<const float4*>(&Bs[k][tx * 4]);
            float4 b1 = *reinterpret_cast<const float4*>(&Bs[k][tx * 4 + 64]);
            float av[8] = {a0.x, a0.y, a0.z, a0.w, a1.x, a1.y, a1.z, a1.w};
            float bv[8] = {b0.x, b0.y, b0.z, b0.w, b1.x, b1.y, b1.z, b1.w};
#pragma unroll
            for (int i = 0; i < 8; ++i)
#pragma unroll
                for (int j = 0; j < 8; ++j)
                    acc[i][j] += av[i] * bv[j];
        }
        __syncthreads();
    }

#pragma unroll
    for (int i = 0; i < 8; ++i) {
        int row = row0 + ((i < 4) ? (ty * 4 + i) : (64 + ty * 4 + i - 4));
        if (row >= V_) continue;
        int c0 = tx * 4, c1 = tx * 4 + 64;
        float4 v0, v1;
        v0.x = acc[i][0] + bp[g * H_ + c0 + 0];
        v0.y = acc[i][1] + bp[g * H_ + c0 + 1];
        v0.z = acc[i][2] + bp[g * H_ + c0 + 2];
        v0.w = acc[i][3] + bp[g * H_ + c0 + 3];
        v1.x = acc[i][4] + bp[g * H_ + c1 + 0];
        v1.y = acc[i][5] + bp[g * H_ + c1 + 1];
        v1.z = acc[i][6] + bp[g * H_ + c1 + 2];
        v1.w = acc[i][7] + bp[g * H_ + c1 + 3];
        *reinterpret_cast<float4*>(&Pg[(size_t)row * H_ + c0]) = v0;
        *reinterpret_cast<float4*>(&Pg[(size_t)row * H_ + c1]) = v1;
    }
}

// ---------------------------------------------------------------------------
// Batched CSR build over all G graphs (grid.y = g):
//   deg_count -> scan1 (block sums) -> scan2 (scan sums) -> scan3 (local scan,
//   writes off, zeroes deg for reuse as cnt) -> scatter
// ---------------------------------------------------------------------------
__global__ __launch_bounds__(256) void deg_count_kernel(const int* __restrict__ dstA,
                                                        int* __restrict__ deg)
{
    const int g = blockIdx.y;
    int e = blockIdx.x * 256 + threadIdx.x;
    if (e < E_) atomicAdd(&deg[g * N_ + dstA[(size_t)g * E_ + e]], 1);
}

__global__ __launch_bounds__(512) void scan1_kernel(const int* __restrict__ deg,
                                                    int* __restrict__ bsum)
{
    __shared__ int sh[512];
    const int g = blockIdx.y, b = blockIdx.x, t = threadIdx.x;
    int i = b * SCB_ + t;
    sh[t] = (i < N_) ? deg[g * N_ + i] : 0;
    __syncthreads();
#pragma unroll
    for (int ofs = 256; ofs > 0; ofs >>= 1) {
        if (t < ofs) sh[t] += sh[t + ofs];
        __syncthreads();
    }
    if (t == 0) bsum[g * NBLK_ + b] = sh[0];
}

__global__ __launch_bounds__(256) void scan2_kernel(const int* __restrict__ bsum,
                                                    int* __restrict__ bpre,
                                                    int* __restrict__ off)
{
    __shared__ int sh[256];
    const int g = blockIdx.x, t = threadIdx.x;
    int v = (t < NBLK_) ? bsum[g * NBLK_ + t] : 0;
    sh[t] = v;
    __syncthreads();
#pragma unroll
    for (int ofs = 1; ofs < 256; ofs <<= 1) {
        int u = (t >= ofs) ? sh[t - ofs] : 0;
        __syncthreads();
        sh[t] += u;
        __syncthreads();
    }
    if (t < NBLK_) bpre[g * (NBLK_ + 1) + t + 1] = sh[t];
    if (t == 0) {
        bpre[g * (NBLK_ + 1)] = 0;
        off[(size_t)g * (N_ + 1) + N_] = sh[NBLK_ - 1];
    }
}

__global__ __launch_bounds__(512) void scan3_kernel(int* __restrict__ deg,
                                                    const int* __restrict__ bpre,
                                                    int* __restrict__ off)
{
    __shared__ int sh[512];
    const int g = blockIdx.y, b = blockIdx.x, t = threadIdx.x;
    int i = b * SCB_ + t;
    int v = (i < N_) ? deg[g * N_ + i] : 0;
    sh[t] = v;
    __syncthreads();
#pragma unroll
    for (int ofs = 1; ofs < 512; ofs <<= 1) {
        int u = (t >= ofs) ? sh[t - ofs] : 0;
        __syncthreads();
        sh[t] += u;
        __syncthreads();
    }
    if (i < N_) {
        off[(size_t)g * (N_ + 1) + i] = bpre[g * (NBLK_ + 1) + b] + sh[t] - v;
        deg[g * N_ + i] = 0;   // becomes cnt for scatter
    }
}

__global__ __launch_bounds__(256) void scatter_kernel(
    const int* __restrict__ srcA, const int* __restrict__ dstA,
    const float* __restrict__ ewA, const float* __restrict__ ep,
    const int* __restrict__ idxA, const int* __restrict__ off,
    int* __restrict__ cnt, int* __restrict__ csr_src,
    int* __restrict__ csr_vsrc, float* __restrict__ csr_coef)
{
    const int g = blockIdx.y;
    int e = blockIdx.x * 256 + threadIdx.x;
    if (e >= E_) return;
    int s = srcA[(size_t)g * E_ + e];
    int d = dstA[(size_t)g * E_ + e];
    int pos = off[(size_t)g * (N_ + 1) + d] + atomicAdd(&cnt[g * N_ + d], 1);
    csr_src[(size_t)g * E_ + pos]  = s;
    csr_vsrc[(size_t)g * E_ + pos] = idxA[(size_t)g * N_ + s];
    float w = ep[g] * ewA[(size_t)g * E_ + e];
    csr_coef[(size_t)g * E_ + pos] = fmaxf(w, 0.f);
}

// ---------------------------------------------------------------------------
// Propagation step 1: hB[n] = P[idx[n]] + inv_deg * sum coef * P[vsrc]
// 32 lanes per node (float4/lane), 8 nodes/block, 4-deep gather pipeline.
// ---------------------------------------------------------------------------
__global__ __launch_bounds__(256) void prop1_kernel(
    const int* __restrict__ idx_g, const int* __restrict__ off,
    const int* __restrict__ csr_vsrc, const float* __restrict__ csr_coef,
    const float* __restrict__ P, float* __restrict__ hB)
{
    const int n = blockIdx.x * 8 + (threadIdx.x >> 5);
    if (n >= N_) return;
    const int lane = threadIdx.x & 31;
    const int col  = lane * 4;

    const int lo = off[n], hi = off[n + 1];
    const float4 self = *reinterpret_cast<const float4*>(
        &P[(size_t)idx_g[n] * H_ + col]);

    float4 acc = make_float4(0.f, 0.f, 0.f, 0.f);
    int i = lo;
    for (; i + 4 <= hi; i += 4) {
        int   s0 = csr_vsrc[i],     s1 = csr_vsrc[i + 1];
        int   s2 = csr_vsrc[i + 2], s3 = csr_vsrc[i + 3];
        float c0 = csr_coef[i],     c1 = csr_coef[i + 1];
        float c2 = csr_coef[i + 2], c3 = csr_coef[i + 3];
        float4 v0 = *reinterpret_cast<const float4*>(&P[(size_t)s0 * H_ + col]);
        float4 v1 = *reinterpret_cast<const float4*>(&P[(size_t)s1 * H_ + col]);
        float4 v2 = *reinterpret_cast<const float4*>(&P[(size_t)s2 * H_ + col]);
        float4 v3 = *reinterpret_cast<const float4*>(&P[(size_t)s3 * H_ + col]);
        acc.x += c0 * v0.x + c1 * v1.x + c2 * v2.x + c3 * v3.x;
        acc.y += c0 * v0.y + c1 * v1.y + c2 * v2.y + c3 * v3.y;
        acc.z += c0 * v0.z + c1 * v1.z + c2 * v2.z + c3 * v3.z;
        acc.w += c0 * v0.w + c1 * v1.w + c2 * v2.w + c3 * v3.w;
    }
    for (; i < hi; ++i) {
        int   s = csr_vsrc[i];
        float c = csr_coef[i];
        float4 v = *reinterpret_cast<const float4*>(&P[(size_t)s * H_ + col]);
        acc.x += c * v.x; acc.y += c * v.y; acc.z += c * v.z; acc.w += c * v.w;
    }
    const float inv = (hi > lo) ? 1.0f / (float)(hi - lo) : 0.f;
    float4 o = make_float4(self.x + inv * acc.x, self.y + inv * acc.y,
                           self.z + inv * acc.z, self.w + inv * acc.w);
    *reinterpret_cast<float4*>(&hB[(size_t)n * H_ + col]) = o;
}

// ---------------------------------------------------------------------------
// Propagation step 2: hA[n] = hB[n] + inv_deg * sum coef * hB[src]
// ---------------------------------------------------------------------------
__global__ __launch_bounds__(256) void prop2_kernel(
    const int* __restrict__ off, const int* __restrict__ csr_src,
    const float* __restrict__ csr_coef,
    const float* __restrict__ h_old, float* __restrict__ h_new)
{
    const int n = blockIdx.x * 8 + (threadIdx.x >> 5);
    if (n >= N_) return;
    const int lane = threadIdx.x & 31;
    const int col  = lane * 4;

    const int lo = off[n], hi = off[n + 1];
    const float4 self = *reinterpret_cast<const float4*>(
        &h_old[(size_t)n * H_ + col]);

    float4 acc = make_float4(0.f, 0.f, 0.f, 0.f);
    int i = lo;
    for (; i + 4 <= hi; i += 4) {
        int   s0 = csr_src[i],     s1 = csr_src[i + 1];
        int   s2 = csr_src[i + 2], s3 = csr_src[i + 3];
        float c0 = csr_coef[i],    c1 = csr_coef[i + 1];
        float c2 = csr_coef[i + 2], c3 = csr_coef[i + 3];
        float4 v0 = *reinterpret_cast<const float4*>(&h_old[(size_t)s0 * H_ + col]);
        float4 v1 = *reinterpret_cast<const float4*>(&h_old[(size_t)s1 * H_ + col]);
        float4 v2 = *reinterpret_cast<const float4*>(&h_old[(size_t)s2 * H_ + col]);
        float4 v3 = *reinterpret_cast<const float4*>(&h_old[(size_t)s3 * H_ + col]);
        acc.x += c0 * v0.x + c1 * v1.x + c2 * v2.x + c3 * v3.x;
        acc.y += c0 * v0.y + c1 * v1.y + c2 * v2.y + c3 * v3.y;
        acc.z += c0 * v0.z + c1 * v1.z + c2 * v2.z + c3 * v3.z;
        acc.w += c0 * v0.w + c1 * v1.w + c2 * v2.w + c3 * v3.w;
    }
    for (; i < hi; ++i) {
        int   s = csr_src[i];
        float c = csr_coef[i];
        float4 v = *reinterpret_cast<const float4*>(&h_old[(size_t)s * H_ + col]);
        acc.x += c * v.x; acc.y += c * v.y; acc.z += c * v.z; acc.w += c * v.w;
    }
    const float inv = (hi > lo) ? 1.0f / (float)(hi - lo) : 0.f;
    float4 o = make_float4(self.x + inv * acc.x, self.y + inv * acc.y,
                           self.z + inv * acc.z, self.w + inv * acc.w);
    *reinterpret_cast<float4*>(&h_new[(size_t)n * H_ + col]) = o;
}

// ---------------------------------------------------------------------------
// Doc pooling + ReLU + classifier
// ---------------------------------------------------------------------------
__global__ __launch_bounds__(128) void doc_cls_kernel(
    const int* __restrict__ gid, const float* __restrict__ h,
    const float* __restrict__ Wc, const float* __restrict__ bc,
    float* __restrict__ logits)
{
    const int b   = blockIdx.x;
    const int tid = threadIdx.x;

    int lo = lower_bound_i(gid, N_, b);
    int hi = lower_bound_i(gid, N_, b + 1);

    float s = 0.f;
    for (int n = lo; n < hi; ++n) s += h[(long)n * H_ + tid];

    float cnt = (float)(hi - lo);
    float doc = s / fmaxf(cnt, 1.0f);

    __shared__ float sdoc[H_];
    sdoc[tid] = fmaxf(doc, 0.f);
    __syncthreads();

    if (tid < C_) {
        float acc = bc[tid];
#pragma unroll 8
        for (int hh = 0; hh < H_; ++hh) acc += sdoc[hh] * Wc[hh * C_ + tid];
        logits[b * C_ + tid] = acc;
    }
}

// ---------------------------------------------------------------------------
// Head fusion + mean over heads + softmax
// ---------------------------------------------------------------------------
__global__ __launch_bounds__(64) void fuse_kernel(
    const float* __restrict__ logits,  // [G][B][C]
    const float* __restrict__ Wf,      // [NH][C][C][G]
    const float* __restrict__ bf,      // [NH][C]
    float* __restrict__ out)
{
    const int b   = blockIdx.x;
    const int tid = threadIdx.x;

    __shared__ float s[C_ * G_];
    __shared__ float fl[C_];

    for (int t = tid; t < C_ * G_; t += 64) {
        int i = t >> 2, g = t & 3;
        s[t] = logits[((long)g * B_ + b) * C_ + i];
    }
    __syncthreads();

    if (tid < C_) {
        float acc = 0.f;
        for (int hd = 0; hd < NH_; ++hd) {
            float a = bf[hd * C_ + tid];
            const float* wrow = &Wf[((hd * C_ + tid) * C_) * G_];
#pragma unroll 5
            for (int i = 0; i < C_; ++i) {
#pragma unroll
                for (int g = 0; g < G_; ++g)
                    a += s[i * G_ + g] * wrow[i * G_ + g];
            }
            acc += a;
        }
        fl[tid] = acc * (1.0f / 3.0f);
    }
    __syncthreads();

    if (tid < C_) {
        float f = fl[tid];
        float m = -1e30f;
#pragma unroll
        for (int i = 0; i < C_; ++i) m = fmaxf(m, fl[i]);
        float ssum = 0.f;
#pragma unroll
        for (int i = 0; i < C_; ++i) ssum += expf(fl[i] - m);
        out[b * C_ + tid] = expf(f - m) / ssum;
        out[B_ * C_ + b * C_ + tid] = f;
    }
}

// ---------------------------------------------------------------------------
extern "C" void kernel_launch(void* const* d_in, const int* in_sizes, int n_in,
                              void* d_out, int out_size, void* d_ws, size_t ws_size,
                              hipStream_t stream)
{
    const int*   node_indices = (const int*)d_in[0];
    const int*   srcA         = (const int*)d_in[1];
    const int*   dstA         = (const int*)d_in[2];
    const int*   gidA         = (const int*)d_in[3];
    const float* ewA          = (const float*)d_in[4];
    const float* emb          = (const float*)d_in[5];
    const float* ep           = (const float*)d_in[6];
    const float* Wp           = (const float*)d_in[7];
    const float* bp           = (const float*)d_in[8];
    const float* Wc           = (const float*)d_in[9];
    const float* bc           = (const float*)d_in[10];
    const float* Wf           = (const float*)d_in[11];
    const float* bf           = (const float*)d_in[12];
    float*       out          = (float*)d_out;

    // Workspace layout (256B-aligned blocks)
    char* wp0 = (char*)d_ws;
    auto alloc = [&](size_t bytes) {
        void* r = (void*)wp0;
        wp0 += (bytes + 255) & ~(size_t)255;
        return r;
    };
    float* hA       = (float*)alloc((size_t)N_ * H_ * 4);
    float* hB       = (float*)alloc((size_t)N_ * H_ * 4);
    float* logits   = (float*)alloc((size_t)G_ * B_ * C_ * 4);
    int*   deg_i    = (int*)  alloc((size_t)G_ * N_ * 4);           // also cnt
    int*   off      = (int*)  alloc((size_t)G_ * (N_ + 1) * 4);
    int*   bsum     = (int*)  alloc((size_t)G_ * NBLK_ * 4);
    int*   bpre     = (int*)  alloc((size_t)G_ * (NBLK_ + 1) * 4);
    int*   csr_src  = (int*)  alloc((size_t)G_ * E_ * 4);
    int*   csr_vsrc = (int*)  alloc((size_t)G_ * E_ * 4);
    float* csr_coef = (float*)alloc((size_t)G_ * E_ * 4);

    const size_t pbytes = (size_t)V_ * H_ * 4;   // 25.6 MB per graph
    size_t used  = (size_t)(wp0 - (char*)d_ws);
    size_t avail = (ws_size > used) ? ws_size - used : 0;

    int ng;
    float* P;
    if (avail >= 4 * pbytes + 1024) {
        ng = 4; P = (float*)alloc(4 * pbytes);
    } else if (avail >= 2 * pbytes + 1024) {
        ng = 2; P = (float*)alloc(2 * pbytes);
    } else {
        // Alias P onto hA (safe: P consumed by prop1 before prop2 writes hA)
        ng = 1; P = hA;
    }

    // ---- batched CSR build for all graphs ----
    hipMemsetAsync(deg_i, 0, (size_t)G_ * N_ * sizeof(int), stream);
    deg_count_kernel<<<dim3((E_ + 255) / 256, G_), 256, 0, stream>>>(dstA, deg_i);
    scan1_kernel<<<dim3(NBLK_, G_), 512, 0, stream>>>(deg_i, bsum);
    scan2_kernel<<<G_, 256, 0, stream>>>(bsum, bpre, off);
    scan3_kernel<<<dim3(NBLK_, G_), 512, 0, stream>>>(deg_i, bpre, off);
    scatter_kernel<<<dim3((E_ + 255) / 256, G_), 256, 0, stream>>>(
        srcA, dstA, ewA, ep, node_indices, off, deg_i, csr_src, csr_vsrc, csr_coef);

    // ---- per-graph-group GEMM + per-graph propagation ----
    for (int gbase = 0; gbase < G_; gbase += ng) {
        table_gemm_kernel<<<dim3(ng, (V_ + 127) / 128), 256, 0, stream>>>(
            emb, Wp + (size_t)gbase * D_ * H_, bp + (size_t)gbase * H_, P);

        for (int gi = 0; gi < ng; ++gi) {
            const int g = gbase + gi;
            const int*   idx   = node_indices + (size_t)g * N_;
            const int*   gid   = gidA + (size_t)g * N_;
            const int*   off_g = off + (size_t)g * (N_ + 1);
            const float* Pg    = P + (size_t)gi * V_ * H_;

            prop1_kernel<<<(N_ + 7) / 8, 256, 0, stream>>>(
                idx, off_g, csr_vsrc + (size_t)g * E_, csr_coef + (size_t)g * E_,
                Pg, hB);
            prop2_kernel<<<(N_ + 7) / 8, 256, 0, stream>>>(
                off_g, csr_src + (size_t)g * E_, csr_coef + (size_t)g * E_,
                hB, hA);

            doc_cls_kernel<<<B_, 128, 0, stream>>>(
                gid, hA, Wc + (size_t)g * H_ * C_, bc + (size_t)g * C_,
                logits + (size_t)g * B_ * C_);
        }
    }

    fuse_kernel<<<B_, 64, 0, stream>>>(logits, Wf, bf, out);
}

// Round 6
// 1161.756 us; speedup vs baseline: 1.0036x; 1.0036x over previous
//
#include <hip/hip_runtime.h>

// Problem constants (match reference)
#define G_  4
#define N_  100000
#define E_  500000
#define B_  512
#define V_  50000
#define D_  300
#define H_  128
#define C_  20
#define NH_ 3

#define SCB_  512                       // elems per scan block
#define NBLK_ ((N_ + SCB_ - 1) / SCB_)  // 196

__device__ __forceinline__ int lower_bound_i(const int* __restrict__ a, int n, int v) {
    int lo = 0, hi = n;
    while (lo < hi) {
        int mid = (lo + hi) >> 1;
        if (a[mid] < v) lo = mid + 1; else hi = mid;
    }
    return lo;
}

// ---------------------------------------------------------------------------
// Table projection GEMM: P[g][v][h] = sum_k emb[v][k] * Wp[g][k][h] + bp[g][h]
// grid = (ng, V/128): blockIdx.x = graph so blocks sharing an A-tile dispatch
// adjacently (L2/L3 A reuse). BM=128, BN=128, BK=16, 8x8/thread.
// ---------------------------------------------------------------------------
__global__ __launch_bounds__(256) void table_gemm_kernel(
    const float* __restrict__ A,    // emb_table [V][300]
    const float* __restrict__ Wp,   // [ng][300][128]
    const float* __restrict__ bp,   // [ng][128]
    float* __restrict__ P)          // [ng][V][128]
{
    __shared__ __align__(16) float As[16][128 + 4];  // As[k][m]
    __shared__ __align__(16) float Bs[16][128 + 4];  // Bs[k][n]

    const int t    = threadIdx.x;
    const int g    = blockIdx.x;
    const int row0 = blockIdx.y * 128;

    const float* Bg = Wp + (size_t)g * D_ * H_;
    float*       Pg = P  + (size_t)g * V_ * H_;

    const int ty = t >> 4;   // 0..15
    const int tx = t & 15;   // 0..15

    float acc[8][8];
#pragma unroll
    for (int i = 0; i < 8; ++i)
#pragma unroll
        for (int j = 0; j < 8; ++j) acc[i][j] = 0.f;

    for (int k0 = 0; k0 < 304; k0 += 16) {
        // --- load A tile (transposed into LDS) ---
#pragma unroll
        for (int i = 0; i < 2; ++i) {
            int flat = t + i * 256;
            int m  = flat >> 2;        // 0..127
            int kq = flat & 3;         // 0..3
            int row = row0 + m;
            int k   = k0 + kq * 4;
            float4 v = make_float4(0.f, 0.f, 0.f, 0.f);
            if (row < V_ && k <= D_ - 4)
                v = *reinterpret_cast<const float4*>(&A[(size_t)row * D_ + k]);
            As[kq * 4 + 0][m] = v.x;
            As[kq * 4 + 1][m] = v.y;
            As[kq * 4 + 2][m] = v.z;
            As[kq * 4 + 3][m] = v.w;
        }
        // --- load B tile ---
#pragma unroll
        for (int i = 0; i < 2; ++i) {
            int flat = t + i * 256;
            int k  = flat >> 5;        // 0..15
            int nq = flat & 31;        // 0..31
            float4 v = make_float4(0.f, 0.f, 0.f, 0.f);
            if (k0 + k < D_)
                v = *reinterpret_cast<const float4*>(&Bg[(size_t)(k0 + k) * H_ + nq * 4]);
            *reinterpret_cast<float4*>(&Bs[k][nq * 4]) = v;
        }
        __syncthreads();

#pragma unroll
        for (int k = 0; k < 16; ++k) {
            float4 a0 = *reinterpret_cast<const float4*>(&As[k][ty * 4]);
            float4 a1 = *reinterpret_cast<const float4*>(&As[k][ty * 4 + 64]);
            float4 b0 = *reinterpret_cast<const float4*>(&Bs[k][tx * 4]);
            float4 b1 = *reinterpret_cast<const float4*>(&Bs[k][tx * 4 + 64]);
            float av[8] = {a0.x, a0.y, a0.z, a0.w, a1.x, a1.y, a1.z, a1.w};
            float bv[8] = {b0.x, b0.y, b0.z, b0.w, b1.x, b1.y, b1.z, b1.w};
#pragma unroll
            for (int i = 0; i < 8; ++i)
#pragma unroll
                for (int j = 0; j < 8; ++j)
                    acc[i][j] += av[i] * bv[j];
        }
        __syncthreads();
    }

#pragma unroll
    for (int i = 0; i < 8; ++i) {
        int row = row0 + ((i < 4) ? (ty * 4 + i) : (64 + ty * 4 + i - 4));
        if (row >= V_) continue;
        int c0 = tx * 4, c1 = tx * 4 + 64;
        float4 v0, v1;
        v0.x = acc[i][0] + bp[g * H_ + c0 + 0];
        v0.y = acc[i][1] + bp[g * H_ + c0 + 1];
        v0.z = acc[i][2] + bp[g * H_ + c0 + 2];
        v0.w = acc[i][3] + bp[g * H_ + c0 + 3];
        v1.x = acc[i][4] + bp[g * H_ + c1 + 0];
        v1.y = acc[i][5] + bp[g * H_ + c1 + 1];
        v1.z = acc[i][6] + bp[g * H_ + c1 + 2];
        v1.w = acc[i][7] + bp[g * H_ + c1 + 3];
        *reinterpret_cast<float4*>(&Pg[(size_t)row * H_ + c0]) = v0;
        *reinterpret_cast<float4*>(&Pg[(size_t)row * H_ + c1]) = v1;
    }
}

// ---------------------------------------------------------------------------
// Batched CSR build over all G graphs (grid.y = g):
//   deg_count -> scan1 (block sums) -> scan2 (scan sums) -> scan3 (local scan,
//   writes off, zeroes deg for reuse as cnt) -> scatter
// ---------------------------------------------------------------------------
__global__ __launch_bounds__(256) void deg_count_kernel(const int* __restrict__ dstA,
                                                        int* __restrict__ deg)
{
    const int g = blockIdx.y;
    int e = blockIdx.x * 256 + threadIdx.x;
    if (e < E_) atomicAdd(&deg[g * N_ + dstA[(size_t)g * E_ + e]], 1);
}

__global__ __launch_bounds__(512) void scan1_kernel(const int* __restrict__ deg,
                                                    int* __restrict__ bsum)
{
    __shared__ int sh[512];
    const int g = blockIdx.y, b = blockIdx.x, t = threadIdx.x;
    int i = b * SCB_ + t;
    sh[t] = (i < N_) ? deg[g * N_ + i] : 0;
    __syncthreads();
#pragma unroll
    for (int ofs = 256; ofs > 0; ofs >>= 1) {
        if (t < ofs) sh[t] += sh[t + ofs];
        __syncthreads();
    }
    if (t == 0) bsum[g * NBLK_ + b] = sh[0];
}

__global__ __launch_bounds__(256) void scan2_kernel(const int* __restrict__ bsum,
                                                    int* __restrict__ bpre,
                                                    int* __restrict__ off)
{
    __shared__ int sh[256];
    const int g = blockIdx.x, t = threadIdx.x;
    int v = (t < NBLK_) ? bsum[g * NBLK_ + t] : 0;
    sh[t] = v;
    __syncthreads();
#pragma unroll
    for (int ofs = 1; ofs < 256; ofs <<= 1) {
        int u = (t >= ofs) ? sh[t - ofs] : 0;
        __syncthreads();
        sh[t] += u;
        __syncthreads();
    }
    if (t < NBLK_) bpre[g * (NBLK_ + 1) + t + 1] = sh[t];
    if (t == 0) {
        bpre[g * (NBLK_ + 1)] = 0;
        off[(size_t)g * (N_ + 1) + N_] = sh[NBLK_ - 1];
    }
}

__global__ __launch_bounds__(512) void scan3_kernel(int* __restrict__ deg,
                                                    const int* __restrict__ bpre,
                                                    int* __restrict__ off)
{
    __shared__ int sh[512];
    const int g = blockIdx.y, b = blockIdx.x, t = threadIdx.x;
    int i = b * SCB_ + t;
    int v = (i < N_) ? deg[g * N_ + i] : 0;
    sh[t] = v;
    __syncthreads();
#pragma unroll
    for (int ofs = 1; ofs < 512; ofs <<= 1) {
        int u = (t >= ofs) ? sh[t - ofs] : 0;
        __syncthreads();
        sh[t] += u;
        __syncthreads();
    }
    if (i < N_) {
        off[(size_t)g * (N_ + 1) + i] = bpre[g * (NBLK_ + 1) + b] + sh[t] - v;
        deg[g * N_ + i] = 0;   // becomes cnt for scatter
    }
}

__global__ __launch_bounds__(256) void scatter_kernel(
    const int* __restrict__ srcA, const int* __restrict__ dstA,
    const float* __restrict__ ewA, const float* __restrict__ ep,
    const int* __restrict__ idxA, const int* __restrict__ off,
    int* __restrict__ cnt, int* __restrict__ csr_src,
    int* __restrict__ csr_vsrc, float* __restrict__ csr_coef)
{
    const int g = blockIdx.y;
    int e = blockIdx.x * 256 + threadIdx.x;
    if (e >= E_) return;
    int s = srcA[(size_t)g * E_ + e];
    int d = dstA[(size_t)g * E_ + e];
    int pos = off[(size_t)g * (N_ + 1) + d] + atomicAdd(&cnt[g * N_ + d], 1);
    csr_src[(size_t)g * E_ + pos]  = s;
    csr_vsrc[(size_t)g * E_ + pos] = idxA[(size_t)g * N_ + s];
    float w = ep[g] * ewA[(size_t)g * E_ + e];
    csr_coef[(size_t)g * E_ + pos] = fmaxf(w, 0.f);
}

// ---------------------------------------------------------------------------
// Propagation step 1: hB[n] = P[idx[n]] + inv_deg * sum coef * P[vsrc]
// 32 lanes per node (float4/lane), 8 nodes/block, 4-deep gather pipeline.
// ---------------------------------------------------------------------------
__global__ __launch_bounds__(256) void prop1_kernel(
    const int* __restrict__ idx_g, const int* __restrict__ off,
    const int* __restrict__ csr_vsrc, const float* __restrict__ csr_coef,
    const float* __restrict__ P, float* __restrict__ hB)
{
    const int n = blockIdx.x * 8 + (threadIdx.x >> 5);
    if (n >= N_) return;
    const int lane = threadIdx.x & 31;
    const int col  = lane * 4;

    const int lo = off[n], hi = off[n + 1];
    const float4 self = *reinterpret_cast<const float4*>(
        &P[(size_t)idx_g[n] * H_ + col]);

    float4 acc = make_float4(0.f, 0.f, 0.f, 0.f);
    int i = lo;
    for (; i + 4 <= hi; i += 4) {
        int   s0 = csr_vsrc[i],     s1 = csr_vsrc[i + 1];
        int   s2 = csr_vsrc[i + 2], s3 = csr_vsrc[i + 3];
        float c0 = csr_coef[i],     c1 = csr_coef[i + 1];
        float c2 = csr_coef[i + 2], c3 = csr_coef[i + 3];
        float4 v0 = *reinterpret_cast<const float4*>(&P[(size_t)s0 * H_ + col]);
        float4 v1 = *reinterpret_cast<const float4*>(&P[(size_t)s1 * H_ + col]);
        float4 v2 = *reinterpret_cast<const float4*>(&P[(size_t)s2 * H_ + col]);
        float4 v3 = *reinterpret_cast<const float4*>(&P[(size_t)s3 * H_ + col]);
        acc.x += c0 * v0.x + c1 * v1.x + c2 * v2.x + c3 * v3.x;
        acc.y += c0 * v0.y + c1 * v1.y + c2 * v2.y + c3 * v3.y;
        acc.z += c0 * v0.z + c1 * v1.z + c2 * v2.z + c3 * v3.z;
        acc.w += c0 * v0.w + c1 * v1.w + c2 * v2.w + c3 * v3.w;
    }
    for (; i < hi; ++i) {
        int   s = csr_vsrc[i];
        float c = csr_coef[i];
        float4 v = *reinterpret_cast<const float4*>(&P[(size_t)s * H_ + col]);
        acc.x += c * v.x; acc.y += c * v.y; acc.z += c * v.z; acc.w += c * v.w;
    }
    const float inv = (hi > lo) ? 1.0f / (float)(hi - lo) : 0.f;
    float4 o = make_float4(self.x + inv * acc.x, self.y + inv * acc.y,
                           self.z + inv * acc.z, self.w + inv * acc.w);
    *reinterpret_cast<float4*>(&hB[(size_t)n * H_ + col]) = o;
}

// ---------------------------------------------------------------------------
// Propagation step 2: hA[n] = hB[n] + inv_deg * sum coef * hB[src]
// ---------------------------------------------------------------------------
__global__ __launch_bounds__(256) void prop2_kernel(
    const int* __restrict__ off, const int* __restrict__ csr_src,
    const float* __restrict__ csr_coef,
    const float* __restrict__ h_old, float* __restrict__ h_new)
{
    const int n = blockIdx.x * 8 + (threadIdx.x >> 5);
    if (n >= N_) return;
    const int lane = threadIdx.x & 31;
    const int col  = lane * 4;

    const int lo = off[n], hi = off[n + 1];
    const float4 self = *reinterpret_cast<const float4*>(
        &h_old[(size_t)n * H_ + col]);

    float4 acc = make_float4(0.f, 0.f, 0.f, 0.f);
    int i = lo;
    for (; i + 4 <= hi; i += 4) {
        int   s0 = csr_src[i],     s1 = csr_src[i + 1];
        int   s2 = csr_src[i + 2], s3 = csr_src[i + 3];
        float c0 = csr_coef[i],    c1 = csr_coef[i + 1];
        float c2 = csr_coef[i + 2], c3 = csr_coef[i + 3];
        float4 v0 = *reinterpret_cast<const float4*>(&h_old[(size_t)s0 * H_ + col]);
        float4 v1 = *reinterpret_cast<const float4*>(&h_old[(size_t)s1 * H_ + col]);
        float4 v2 = *reinterpret_cast<const float4*>(&h_old[(size_t)s2 * H_ + col]);
        float4 v3 = *reinterpret_cast<const float4*>(&h_old[(size_t)s3 * H_ + col]);
        acc.x += c0 * v0.x + c1 * v1.x + c2 * v2.x + c3 * v3.x;
        acc.y += c0 * v0.y + c1 * v1.y + c2 * v2.y + c3 * v3.y;
        acc.z += c0 * v0.z + c1 * v1.z + c2 * v2.z + c3 * v3.z;
        acc.w += c0 * v0.w + c1 * v1.w + c2 * v2.w + c3 * v3.w;
    }
    for (; i < hi; ++i) {
        int   s = csr_src[i];
        float c = csr_coef[i];
        float4 v = *reinterpret_cast<const float4*>(&h_old[(size_t)s * H_ + col]);
        acc.x += c * v.x; acc.y += c * v.y; acc.z += c * v.z; acc.w += c * v.w;
    }
    const float inv = (hi > lo) ? 1.0f / (float)(hi - lo) : 0.f;
    float4 o = make_float4(self.x + inv * acc.x, self.y + inv * acc.y,
                           self.z + inv * acc.z, self.w + inv * acc.w);
    *reinterpret_cast<float4*>(&h_new[(size_t)n * H_ + col]) = o;
}

// ---------------------------------------------------------------------------
// Doc pooling + ReLU + classifier
// ---------------------------------------------------------------------------
__global__ __launch_bounds__(128) void doc_cls_kernel(
    const int* __restrict__ gid, const float* __restrict__ h,
    const float* __restrict__ Wc, const float* __restrict__ bc,
    float* __restrict__ logits)
{
    const int b   = blockIdx.x;
    const int tid = threadIdx.x;

    int lo = lower_bound_i(gid, N_, b);
    int hi = lower_bound_i(gid, N_, b + 1);

    float s = 0.f;
    for (int n = lo; n < hi; ++n) s += h[(long)n * H_ + tid];

    float cnt = (float)(hi - lo);
    float doc = s / fmaxf(cnt, 1.0f);

    __shared__ float sdoc[H_];
    sdoc[tid] = fmaxf(doc, 0.f);
    __syncthreads();

    if (tid < C_) {
        float acc = bc[tid];
#pragma unroll 8
        for (int hh = 0; hh < H_; ++hh) acc += sdoc[hh] * Wc[hh * C_ + tid];
        logits[b * C_ + tid] = acc;
    }
}

// ---------------------------------------------------------------------------
// Head fusion + mean over heads + softmax
// ---------------------------------------------------------------------------
__global__ __launch_bounds__(64) void fuse_kernel(
    const float* __restrict__ logits,  // [G][B][C]
    const float* __restrict__ Wf,      // [NH][C][C][G]
    const float* __restrict__ bf,      // [NH][C]
    float* __restrict__ out)
{
    const int b   = blockIdx.x;
    const int tid = threadIdx.x;

    __shared__ float s[C_ * G_];
    __shared__ float fl[C_];

    for (int t = tid; t < C_ * G_; t += 64) {
        int i = t >> 2, g = t & 3;
        s[t] = logits[((long)g * B_ + b) * C_ + i];
    }
    __syncthreads();

    if (tid < C_) {
        float acc = 0.f;
        for (int hd = 0; hd < NH_; ++hd) {
            float a = bf[hd * C_ + tid];
            const float* wrow = &Wf[((hd * C_ + tid) * C_) * G_];
#pragma unroll 5
            for (int i = 0; i < C_; ++i) {
#pragma unroll
                for (int g = 0; g < G_; ++g)
                    a += s[i * G_ + g] * wrow[i * G_ + g];
            }
            acc += a;
        }
        fl[tid] = acc * (1.0f / 3.0f);
    }
    __syncthreads();

    if (tid < C_) {
        float f = fl[tid];
        float m = -1e30f;
#pragma unroll
        for (int i = 0; i < C_; ++i) m = fmaxf(m, fl[i]);
        float ssum = 0.f;
#pragma unroll
        for (int i = 0; i < C_; ++i) ssum += expf(fl[i] - m);
        out[b * C_ + tid] = expf(f - m) / ssum;
        out[B_ * C_ + b * C_ + tid] = f;
    }
}

// ---------------------------------------------------------------------------
extern "C" void kernel_launch(void* const* d_in, const int* in_sizes, int n_in,
                              void* d_out, int out_size, void* d_ws, size_t ws_size,
                              hipStream_t stream)
{
    const int*   node_indices = (const int*)d_in[0];
    const int*   srcA         = (const int*)d_in[1];
    const int*   dstA         = (const int*)d_in[2];
    const int*   gidA         = (const int*)d_in[3];
    const float* ewA          = (const float*)d_in[4];
    const float* emb          = (const float*)d_in[5];
    const float* ep           = (const float*)d_in[6];
    const float* Wp           = (const float*)d_in[7];
    const float* bp           = (const float*)d_in[8];
    const float* Wc           = (const float*)d_in[9];
    const float* bc           = (const float*)d_in[10];
    const float* Wf           = (const float*)d_in[11];
    const float* bf           = (const float*)d_in[12];
    float*       out          = (float*)d_out;

    // Workspace layout (256B-aligned blocks)
    char* wp0 = (char*)d_ws;
    auto alloc = [&](size_t bytes) {
        void* r = (void*)wp0;
        wp0 += (bytes + 255) & ~(size_t)255;
        return r;
    };
    float* hA       = (float*)alloc((size_t)N_ * H_ * 4);
    float* hB       = (float*)alloc((size_t)N_ * H_ * 4);
    float* logits   = (float*)alloc((size_t)G_ * B_ * C_ * 4);
    int*   deg_i    = (int*)  alloc((size_t)G_ * N_ * 4);           // also cnt
    int*   off      = (int*)  alloc((size_t)G_ * (N_ + 1) * 4);
    int*   bsum     = (int*)  alloc((size_t)G_ * NBLK_ * 4);
    int*   bpre     = (int*)  alloc((size_t)G_ * (NBLK_ + 1) * 4);
    int*   csr_src  = (int*)  alloc((size_t)G_ * E_ * 4);
    int*   csr_vsrc = (int*)  alloc((size_t)G_ * E_ * 4);
    float* csr_coef = (float*)alloc((size_t)G_ * E_ * 4);

    const size_t pbytes = (size_t)V_ * H_ * 4;   // 25.6 MB per graph
    size_t used  = (size_t)(wp0 - (char*)d_ws);
    size_t avail = (ws_size > used) ? ws_size - used : 0;

    int ng;
    float* P;
    if (avail >= 4 * pbytes + 1024) {
        ng = 4; P = (float*)alloc(4 * pbytes);
    } else if (avail >= 2 * pbytes + 1024) {
        ng = 2; P = (float*)alloc(2 * pbytes);
    } else {
        // Alias P onto hA (safe: P consumed by prop1 before prop2 writes hA)
        ng = 1; P = hA;
    }

    // ---- batched CSR build for all graphs ----
    hipMemsetAsync(deg_i, 0, (size_t)G_ * N_ * sizeof(int), stream);
    deg_count_kernel<<<dim3((E_ + 255) / 256, G_), 256, 0, stream>>>(dstA, deg_i);
    scan1_kernel<<<dim3(NBLK_, G_), 512, 0, stream>>>(deg_i, bsum);
    scan2_kernel<<<G_, 256, 0, stream>>>(bsum, bpre, off);
    scan3_kernel<<<dim3(NBLK_, G_), 512, 0, stream>>>(deg_i, bpre, off);
    scatter_kernel<<<dim3((E_ + 255) / 256, G_), 256, 0, stream>>>(
        srcA, dstA, ewA, ep, node_indices, off, deg_i, csr_src, csr_vsrc, csr_coef);

    // ---- per-graph-group GEMM + per-graph propagation ----
    for (int gbase = 0; gbase < G_; gbase += ng) {
        table_gemm_kernel<<<dim3(ng, (V_ + 127) / 128), 256, 0, stream>>>(
            emb, Wp + (size_t)gbase * D_ * H_, bp + (size_t)gbase * H_, P);

        for (int gi = 0; gi < ng; ++gi) {
            const int g = gbase + gi;
            const int*   idx   = node_indices + (size_t)g * N_;
            const int*   gid   = gidA + (size_t)g * N_;
            const int*   off_g = off + (size_t)g * (N_ + 1);
            const float* Pg    = P + (size_t)gi * V_ * H_;

            prop1_kernel<<<(N_ + 7) / 8, 256, 0, stream>>>(
                idx, off_g, csr_vsrc + (size_t)g * E_, csr_coef + (size_t)g * E_,
                Pg, hB);
            prop2_kernel<<<(N_ + 7) / 8, 256, 0, stream>>>(
                off_g, csr_src + (size_t)g * E_, csr_coef + (size_t)g * E_,
                hB, hA);

            doc_cls_kernel<<<B_, 128, 0, stream>>>(
                gid, hA, Wc + (size_t)g * H_ * C_, bc + (size_t)g * C_,
                logits + (size_t)g * B_ * C_);
        }
    }

    fuse_kernel<<<B_, 64, 0, stream>>>(logits, Wf, bf, out);
}

// Round 7
// 804.348 us; speedup vs baseline: 1.4495x; 1.4443x over previous
//
#include <hip/hip_runtime.h>

// Problem constants (match reference)
#define G_  4
#define N_  100000
#define E_  500000
#define B_  512
#define V_  50000
#define D_  300
#define H_  128
#define C_  20
#define NH_ 3

#define SCB_  512                       // elems per scan block
#define NBLK_ ((N_ + SCB_ - 1) / SCB_)  // 196

typedef unsigned short ushort_t;

__device__ __forceinline__ float bf2f(ushort_t u) {
    return __uint_as_float(((unsigned int)u) << 16);
}
__device__ __forceinline__ ushort_t f2bf(float f) {
    unsigned int x = __float_as_uint(f);
    unsigned int r = x + 0x7FFFu + ((x >> 16) & 1u);   // RNE
    return (ushort_t)(r >> 16);
}

__device__ __forceinline__ int lower_bound_i(const int* __restrict__ a, int n, int v) {
    int lo = 0, hi = n;
    while (lo < hi) {
        int mid = (lo + hi) >> 1;
        if (a[mid] < v) lo = mid + 1; else hi = mid;
    }
    return lo;
}

// unpack 8 bf16 (uint4) -> 8 floats
__device__ __forceinline__ void unpack8(uint4 u, float* f) {
    f[0] = __uint_as_float((u.x & 0xFFFFu) << 16);
    f[1] = __uint_as_float(u.x & 0xFFFF0000u);
    f[2] = __uint_as_float((u.y & 0xFFFFu) << 16);
    f[3] = __uint_as_float(u.y & 0xFFFF0000u);
    f[4] = __uint_as_float((u.z & 0xFFFFu) << 16);
    f[5] = __uint_as_float(u.z & 0xFFFF0000u);
    f[6] = __uint_as_float((u.w & 0xFFFFu) << 16);
    f[7] = __uint_as_float(u.w & 0xFFFF0000u);
}

// ---------------------------------------------------------------------------
// Table projection GEMM: P[g][v][h] = sum_k emb[v][k] * Wp[g][k][h] + bp[g][h]
// fp32 math, bf16 output (Ph). BM=128, BN=128, BK=16, 8x8/thread.
// ---------------------------------------------------------------------------
__global__ __launch_bounds__(256) void table_gemm_kernel(
    const float* __restrict__ A,    // emb_table [V][300]
    const float* __restrict__ Wp,   // [ng][300][128]
    const float* __restrict__ bp,   // [ng][128]
    ushort_t* __restrict__ Ph)      // [ng][V][128] bf16
{
    __shared__ __align__(16) float As[16][128 + 4];  // As[k][m]
    __shared__ __align__(16) float Bs[16][128 + 4];  // Bs[k][n]

    const int t    = threadIdx.x;
    const int g    = blockIdx.x;
    const int row0 = blockIdx.y * 128;

    const float* Bg  = Wp + (size_t)g * D_ * H_;
    ushort_t*    Pg  = Ph + (size_t)g * V_ * H_;

    const int ty = t >> 4;   // 0..15
    const int tx = t & 15;   // 0..15

    float acc[8][8];
#pragma unroll
    for (int i = 0; i < 8; ++i)
#pragma unroll
        for (int j = 0; j < 8; ++j) acc[i][j] = 0.f;

    for (int k0 = 0; k0 < 304; k0 += 16) {
        // --- load A tile (transposed into LDS) ---
#pragma unroll
        for (int i = 0; i < 2; ++i) {
            int flat = t + i * 256;
            int m  = flat >> 2;
            int kq = flat & 3;
            int row = row0 + m;
            int k   = k0 + kq * 4;
            float4 v = make_float4(0.f, 0.f, 0.f, 0.f);
            if (row < V_ && k <= D_ - 4)
                v = *reinterpret_cast<const float4*>(&A[(size_t)row * D_ + k]);
            As[kq * 4 + 0][m] = v.x;
            As[kq * 4 + 1][m] = v.y;
            As[kq * 4 + 2][m] = v.z;
            As[kq * 4 + 3][m] = v.w;
        }
        // --- load B tile ---
#pragma unroll
        for (int i = 0; i < 2; ++i) {
            int flat = t + i * 256;
            int k  = flat >> 5;
            int nq = flat & 31;
            float4 v = make_float4(0.f, 0.f, 0.f, 0.f);
            if (k0 + k < D_)
                v = *reinterpret_cast<const float4*>(&Bg[(size_t)(k0 + k) * H_ + nq * 4]);
            *reinterpret_cast<float4*>(&Bs[k][nq * 4]) = v;
        }
        __syncthreads();

#pragma unroll
        for (int k = 0; k < 16; ++k) {
            float4 a0 = *reinterpret_cast<const float4*>(&As[k][ty * 4]);
            float4 a1 = *reinterpret_cast<const float4*>(&As[k][ty * 4 + 64]);
            float4 b0 = *reinterpret_cast<const float4*>(&Bs[k][tx * 4]);
            float4 b1 = *reinterpret_cast<const float4*>(&Bs[k][tx * 4 + 64]);
            float av[8] = {a0.x, a0.y, a0.z, a0.w, a1.x, a1.y, a1.z, a1.w};
            float bv[8] = {b0.x, b0.y, b0.z, b0.w, b1.x, b1.y, b1.z, b1.w};
#pragma unroll
            for (int i = 0; i < 8; ++i)
#pragma unroll
                for (int j = 0; j < 8; ++j)
                    acc[i][j] += av[i] * bv[j];
        }
        __syncthreads();
    }

#pragma unroll
    for (int i = 0; i < 8; ++i) {
        int row = row0 + ((i < 4) ? (ty * 4 + i) : (64 + ty * 4 + i - 4));
        if (row >= V_) continue;
        int c0 = tx * 4, c1 = tx * 4 + 64;
        ushort_t p[8];
#pragma unroll
        for (int j = 0; j < 4; ++j) p[j]     = f2bf(acc[i][j]     + bp[g * H_ + c0 + j]);
#pragma unroll
        for (int j = 0; j < 4; ++j) p[4 + j] = f2bf(acc[i][4 + j] + bp[g * H_ + c1 + j]);
        uint2 u0, u1;
        u0.x = (unsigned)p[0] | ((unsigned)p[1] << 16);
        u0.y = (unsigned)p[2] | ((unsigned)p[3] << 16);
        u1.x = (unsigned)p[4] | ((unsigned)p[5] << 16);
        u1.y = (unsigned)p[6] | ((unsigned)p[7] << 16);
        *reinterpret_cast<uint2*>(&Pg[(size_t)row * H_ + c0]) = u0;
        *reinterpret_cast<uint2*>(&Pg[(size_t)row * H_ + c1]) = u1;
    }
}

// ---------------------------------------------------------------------------
// Batched CSR build over all G graphs (grid.y = g)
// ---------------------------------------------------------------------------
__global__ __launch_bounds__(256) void deg_count_kernel(const int* __restrict__ dstA,
                                                        int* __restrict__ deg)
{
    const int g = blockIdx.y;
    int e = blockIdx.x * 256 + threadIdx.x;
    if (e < E_) atomicAdd(&deg[g * N_ + dstA[(size_t)g * E_ + e]], 1);
}

__global__ __launch_bounds__(512) void scan1_kernel(const int* __restrict__ deg,
                                                    int* __restrict__ bsum)
{
    __shared__ int sh[512];
    const int g = blockIdx.y, b = blockIdx.x, t = threadIdx.x;
    int i = b * SCB_ + t;
    sh[t] = (i < N_) ? deg[g * N_ + i] : 0;
    __syncthreads();
#pragma unroll
    for (int ofs = 256; ofs > 0; ofs >>= 1) {
        if (t < ofs) sh[t] += sh[t + ofs];
        __syncthreads();
    }
    if (t == 0) bsum[g * NBLK_ + b] = sh[0];
}

__global__ __launch_bounds__(256) void scan2_kernel(const int* __restrict__ bsum,
                                                    int* __restrict__ bpre,
                                                    int* __restrict__ off)
{
    __shared__ int sh[256];
    const int g = blockIdx.x, t = threadIdx.x;
    int v = (t < NBLK_) ? bsum[g * NBLK_ + t] : 0;
    sh[t] = v;
    __syncthreads();
#pragma unroll
    for (int ofs = 1; ofs < 256; ofs <<= 1) {
        int u = (t >= ofs) ? sh[t - ofs] : 0;
        __syncthreads();
        sh[t] += u;
        __syncthreads();
    }
    if (t < NBLK_) bpre[g * (NBLK_ + 1) + t + 1] = sh[t];
    if (t == 0) {
        bpre[g * (NBLK_ + 1)] = 0;
        off[(size_t)g * (N_ + 1) + N_] = sh[NBLK_ - 1];
    }
}

__global__ __launch_bounds__(512) void scan3_kernel(int* __restrict__ deg,
                                                    const int* __restrict__ bpre,
                                                    int* __restrict__ off)
{
    __shared__ int sh[512];
    const int g = blockIdx.y, b = blockIdx.x, t = threadIdx.x;
    int i = b * SCB_ + t;
    int v = (i < N_) ? deg[g * N_ + i] : 0;
    sh[t] = v;
    __syncthreads();
#pragma unroll
    for (int ofs = 1; ofs < 512; ofs <<= 1) {
        int u = (t >= ofs) ? sh[t - ofs] : 0;
        __syncthreads();
        sh[t] += u;
        __syncthreads();
    }
    if (i < N_) {
        off[(size_t)g * (N_ + 1) + i] = bpre[g * (NBLK_ + 1) + b] + sh[t] - v;
        deg[g * N_ + i] = 0;   // becomes cnt for scatter
    }
}

__global__ __launch_bounds__(256) void scatter_kernel(
    const int* __restrict__ srcA, const int* __restrict__ dstA,
    const float* __restrict__ ewA, const float* __restrict__ ep,
    const int* __restrict__ idxA, const int* __restrict__ off,
    int* __restrict__ cnt, int* __restrict__ csr_src,
    int* __restrict__ csr_vsrc, float* __restrict__ csr_coef)
{
    const int g = blockIdx.y;
    int e = blockIdx.x * 256 + threadIdx.x;
    if (e >= E_) return;
    int s = srcA[(size_t)g * E_ + e];
    int d = dstA[(size_t)g * E_ + e];
    int pos = off[(size_t)g * (N_ + 1) + d] + atomicAdd(&cnt[g * N_ + d], 1);
    csr_src[(size_t)g * E_ + pos]  = s;
    csr_vsrc[(size_t)g * E_ + pos] = idxA[(size_t)g * N_ + s];
    float w = ep[g] * ewA[(size_t)g * E_ + e];
    csr_coef[(size_t)g * E_ + pos] = fmaxf(w, 0.f);
}

// ---------------------------------------------------------------------------
// Propagation step 1: hBh[n] = bf16( P[idx[n]] + inv_deg * sum coef * P[vsrc] )
// bf16 rows (256 B); 16 lanes/node (ushort8 = 16 B per lane); 16 nodes/block.
// ---------------------------------------------------------------------------
__global__ __launch_bounds__(256) void prop1_kernel(
    const int* __restrict__ idx_g, const int* __restrict__ off,
    const int* __restrict__ csr_vsrc, const float* __restrict__ csr_coef,
    const ushort_t* __restrict__ Ph, ushort_t* __restrict__ hBh)
{
    const int n = blockIdx.x * 16 + (threadIdx.x >> 4);
    if (n >= N_) return;
    const int lane = threadIdx.x & 15;
    const int col  = lane * 8;

    const int lo = off[n], hi = off[n + 1];

    float sf[8];
    unpack8(*reinterpret_cast<const uint4*>(&Ph[(size_t)idx_g[n] * H_ + col]), sf);

    float acc[8];
#pragma unroll
    for (int j = 0; j < 8; ++j) acc[j] = 0.f;

    int i = lo;
    for (; i + 4 <= hi; i += 4) {
        int   s0 = csr_vsrc[i],     s1 = csr_vsrc[i + 1];
        int   s2 = csr_vsrc[i + 2], s3 = csr_vsrc[i + 3];
        float c0 = csr_coef[i],     c1 = csr_coef[i + 1];
        float c2 = csr_coef[i + 2], c3 = csr_coef[i + 3];
        uint4 u0 = *reinterpret_cast<const uint4*>(&Ph[(size_t)s0 * H_ + col]);
        uint4 u1 = *reinterpret_cast<const uint4*>(&Ph[(size_t)s1 * H_ + col]);
        uint4 u2 = *reinterpret_cast<const uint4*>(&Ph[(size_t)s2 * H_ + col]);
        uint4 u3 = *reinterpret_cast<const uint4*>(&Ph[(size_t)s3 * H_ + col]);
        float f0[8], f1[8], f2[8], f3[8];
        unpack8(u0, f0); unpack8(u1, f1); unpack8(u2, f2); unpack8(u3, f3);
#pragma unroll
        for (int j = 0; j < 8; ++j)
            acc[j] += c0 * f0[j] + c1 * f1[j] + c2 * f2[j] + c3 * f3[j];
    }
    for (; i < hi; ++i) {
        int   s = csr_vsrc[i];
        float c = csr_coef[i];
        float f[8];
        unpack8(*reinterpret_cast<const uint4*>(&Ph[(size_t)s * H_ + col]), f);
#pragma unroll
        for (int j = 0; j < 8; ++j) acc[j] += c * f[j];
    }

    const float inv = (hi > lo) ? 1.0f / (float)(hi - lo) : 0.f;
    ushort_t p[8];
#pragma unroll
    for (int j = 0; j < 8; ++j) p[j] = f2bf(sf[j] + inv * acc[j]);
    uint4 o;
    o.x = (unsigned)p[0] | ((unsigned)p[1] << 16);
    o.y = (unsigned)p[2] | ((unsigned)p[3] << 16);
    o.z = (unsigned)p[4] | ((unsigned)p[5] << 16);
    o.w = (unsigned)p[6] | ((unsigned)p[7] << 16);
    *reinterpret_cast<uint4*>(&hBh[(size_t)n * H_ + col]) = o;
}

// ---------------------------------------------------------------------------
// Propagation step 2: hA[n] = hBh[n] + inv_deg * sum coef * hBh[src]  (fp32 out)
// ---------------------------------------------------------------------------
__global__ __launch_bounds__(256) void prop2_kernel(
    const int* __restrict__ off, const int* __restrict__ csr_src,
    const float* __restrict__ csr_coef,
    const ushort_t* __restrict__ hBh, float* __restrict__ hA)
{
    const int n = blockIdx.x * 16 + (threadIdx.x >> 4);
    if (n >= N_) return;
    const int lane = threadIdx.x & 15;
    const int col  = lane * 8;

    const int lo = off[n], hi = off[n + 1];

    float sf[8];
    unpack8(*reinterpret_cast<const uint4*>(&hBh[(size_t)n * H_ + col]), sf);

    float acc[8];
#pragma unroll
    for (int j = 0; j < 8; ++j) acc[j] = 0.f;

    int i = lo;
    for (; i + 4 <= hi; i += 4) {
        int   s0 = csr_src[i],     s1 = csr_src[i + 1];
        int   s2 = csr_src[i + 2], s3 = csr_src[i + 3];
        float c0 = csr_coef[i],    c1 = csr_coef[i + 1];
        float c2 = csr_coef[i + 2], c3 = csr_coef[i + 3];
        uint4 u0 = *reinterpret_cast<const uint4*>(&hBh[(size_t)s0 * H_ + col]);
        uint4 u1 = *reinterpret_cast<const uint4*>(&hBh[(size_t)s1 * H_ + col]);
        uint4 u2 = *reinterpret_cast<const uint4*>(&hBh[(size_t)s2 * H_ + col]);
        uint4 u3 = *reinterpret_cast<const uint4*>(&hBh[(size_t)s3 * H_ + col]);
        float f0[8], f1[8], f2[8], f3[8];
        unpack8(u0, f0); unpack8(u1, f1); unpack8(u2, f2); unpack8(u3, f3);
#pragma unroll
        for (int j = 0; j < 8; ++j)
            acc[j] += c0 * f0[j] + c1 * f1[j] + c2 * f2[j] + c3 * f3[j];
    }
    for (; i < hi; ++i) {
        int   s = csr_src[i];
        float c = csr_coef[i];
        float f[8];
        unpack8(*reinterpret_cast<const uint4*>(&hBh[(size_t)s * H_ + col]), f);
#pragma unroll
        for (int j = 0; j < 8; ++j) acc[j] += c * f[j];
    }

    const float inv = (hi > lo) ? 1.0f / (float)(hi - lo) : 0.f;
    float4 o0, o1;
    o0.x = sf[0] + inv * acc[0]; o0.y = sf[1] + inv * acc[1];
    o0.z = sf[2] + inv * acc[2]; o0.w = sf[3] + inv * acc[3];
    o1.x = sf[4] + inv * acc[4]; o1.y = sf[5] + inv * acc[5];
    o1.z = sf[6] + inv * acc[6]; o1.w = sf[7] + inv * acc[7];
    *reinterpret_cast<float4*>(&hA[(size_t)n * H_ + col])     = o0;
    *reinterpret_cast<float4*>(&hA[(size_t)n * H_ + col + 4]) = o1;
}

// ---------------------------------------------------------------------------
// Doc pooling + ReLU + classifier
// ---------------------------------------------------------------------------
__global__ __launch_bounds__(128) void doc_cls_kernel(
    const int* __restrict__ gid, const float* __restrict__ h,
    const float* __restrict__ Wc, const float* __restrict__ bc,
    float* __restrict__ logits)
{
    const int b   = blockIdx.x;
    const int tid = threadIdx.x;

    int lo = lower_bound_i(gid, N_, b);
    int hi = lower_bound_i(gid, N_, b + 1);

    float s0 = 0.f, s1 = 0.f;
    int n = lo;
    for (; n + 2 <= hi; n += 2) {
        s0 += h[(long)n * H_ + tid];
        s1 += h[(long)(n + 1) * H_ + tid];
    }
    if (n < hi) s0 += h[(long)n * H_ + tid];
    float s = s0 + s1;

    float cnt = (float)(hi - lo);
    float doc = s / fmaxf(cnt, 1.0f);

    __shared__ float sdoc[H_];
    sdoc[tid] = fmaxf(doc, 0.f);
    __syncthreads();

    if (tid < C_) {
        float acc = bc[tid];
#pragma unroll 8
        for (int hh = 0; hh < H_; ++hh) acc += sdoc[hh] * Wc[hh * C_ + tid];
        logits[b * C_ + tid] = acc;
    }
}

// ---------------------------------------------------------------------------
// Head fusion + mean over heads + softmax
// ---------------------------------------------------------------------------
__global__ __launch_bounds__(64) void fuse_kernel(
    const float* __restrict__ logits,  // [G][B][C]
    const float* __restrict__ Wf,      // [NH][C][C][G]
    const float* __restrict__ bf,      // [NH][C]
    float* __restrict__ out)
{
    const int b   = blockIdx.x;
    const int tid = threadIdx.x;

    __shared__ float s[C_ * G_];
    __shared__ float fl[C_];

    for (int t = tid; t < C_ * G_; t += 64) {
        int i = t >> 2, g = t & 3;
        s[t] = logits[((long)g * B_ + b) * C_ + i];
    }
    __syncthreads();

    if (tid < C_) {
        float acc = 0.f;
        for (int hd = 0; hd < NH_; ++hd) {
            float a = bf[hd * C_ + tid];
            const float* wrow = &Wf[((hd * C_ + tid) * C_) * G_];
#pragma unroll 5
        for (int i = 0; i < C_; ++i) {
#pragma unroll
                for (int g = 0; g < G_; ++g)
                    a += s[i * G_ + g] * wrow[i * G_ + g];
            }
            acc += a;
        }
        fl[tid] = acc * (1.0f / 3.0f);
    }
    __syncthreads();

    if (tid < C_) {
        float f = fl[tid];
        float m = -1e30f;
#pragma unroll
        for (int i = 0; i < C_; ++i) m = fmaxf(m, fl[i]);
        float ssum = 0.f;
#pragma unroll
        for (int i = 0; i < C_; ++i) ssum += expf(fl[i] - m);
        out[b * C_ + tid] = expf(f - m) / ssum;
        out[B_ * C_ + b * C_ + tid] = f;
    }
}

// ---------------------------------------------------------------------------
extern "C" void kernel_launch(void* const* d_in, const int* in_sizes, int n_in,
                              void* d_out, int out_size, void* d_ws, size_t ws_size,
                              hipStream_t stream)
{
    const int*   node_indices = (const int*)d_in[0];
    const int*   srcA         = (const int*)d_in[1];
    const int*   dstA         = (const int*)d_in[2];
    const int*   gidA         = (const int*)d_in[3];
    const float* ewA          = (const float*)d_in[4];
    const float* emb          = (const float*)d_in[5];
    const float* ep           = (const float*)d_in[6];
    const float* Wp           = (const float*)d_in[7];
    const float* bp           = (const float*)d_in[8];
    const float* Wc           = (const float*)d_in[9];
    const float* bc           = (const float*)d_in[10];
    const float* Wf           = (const float*)d_in[11];
    const float* bf           = (const float*)d_in[12];
    float*       out          = (float*)d_out;

    // Workspace layout (256B-aligned blocks)
    char* wp0 = (char*)d_ws;
    auto alloc = [&](size_t bytes) {
        void* r = (void*)wp0;
        wp0 += (bytes + 255) & ~(size_t)255;
        return r;
    };
    float*    hA       = (float*)   alloc((size_t)N_ * H_ * 4);   // 51.2 MB
    ushort_t* hBh      = (ushort_t*)alloc((size_t)N_ * H_ * 2);   // 25.6 MB
    float*    logits   = (float*)   alloc((size_t)G_ * B_ * C_ * 4);
    int*      deg_i    = (int*)     alloc((size_t)G_ * N_ * 4);
    int*      off      = (int*)     alloc((size_t)G_ * (N_ + 1) * 4);
    int*      bsum     = (int*)     alloc((size_t)G_ * NBLK_ * 4);
    int*      bpre     = (int*)     alloc((size_t)G_ * (NBLK_ + 1) * 4);
    int*      csr_src  = (int*)     alloc((size_t)G_ * E_ * 4);
    int*      csr_vsrc = (int*)     alloc((size_t)G_ * E_ * 4);
    float*    csr_coef = (float*)   alloc((size_t)G_ * E_ * 4);

    const size_t pbytes = (size_t)V_ * H_ * 2;   // 12.8 MB per graph (bf16)
    size_t used  = (size_t)(wp0 - (char*)d_ws);
    size_t avail = (ws_size > used) ? ws_size - used : 0;

    int ng;
    ushort_t* Ph;
    if (avail >= 4 * pbytes + 1024) {
        ng = 4; Ph = (ushort_t*)alloc(4 * pbytes);
    } else if (avail >= 2 * pbytes + 1024) {
        ng = 2; Ph = (ushort_t*)alloc(2 * pbytes);
    } else {
        // Alias Ph onto hA (12.8 MB < 51.2 MB). Safe per-graph: Ph consumed by
        // prop1 before prop2 writes hA; GEMM refills Ph next graph.
        ng = 1; Ph = (ushort_t*)hA;
    }

    // ---- batched CSR build for all graphs ----
    hipMemsetAsync(deg_i, 0, (size_t)G_ * N_ * sizeof(int), stream);
    deg_count_kernel<<<dim3((E_ + 255) / 256, G_), 256, 0, stream>>>(dstA, deg_i);
    scan1_kernel<<<dim3(NBLK_, G_), 512, 0, stream>>>(deg_i, bsum);
    scan2_kernel<<<G_, 256, 0, stream>>>(bsum, bpre, off);
    scan3_kernel<<<dim3(NBLK_, G_), 512, 0, stream>>>(deg_i, bpre, off);
    scatter_kernel<<<dim3((E_ + 255) / 256, G_), 256, 0, stream>>>(
        srcA, dstA, ewA, ep, node_indices, off, deg_i, csr_src, csr_vsrc, csr_coef);

    // ---- per-graph-group GEMM + per-graph propagation ----
    for (int gbase = 0; gbase < G_; gbase += ng) {
        table_gemm_kernel<<<dim3(ng, (V_ + 127) / 128), 256, 0, stream>>>(
            emb, Wp + (size_t)gbase * D_ * H_, bp + (size_t)gbase * H_, Ph);

        for (int gi = 0; gi < ng; ++gi) {
            const int g = gbase + gi;
            const int*      idx   = node_indices + (size_t)g * N_;
            const int*      gid   = gidA + (size_t)g * N_;
            const int*      off_g = off + (size_t)g * (N_ + 1);
            const ushort_t* Pg    = Ph + (size_t)gi * V_ * H_;

            prop1_kernel<<<(N_ + 15) / 16, 256, 0, stream>>>(
                idx, off_g, csr_vsrc + (size_t)g * E_, csr_coef + (size_t)g * E_,
                Pg, hBh);
            prop2_kernel<<<(N_ + 15) / 16, 256, 0, stream>>>(
                off_g, csr_src + (size_t)g * E_, csr_coef + (size_t)g * E_,
                hBh, hA);

            doc_cls_kernel<<<B_, 128, 0, stream>>>(
                gid, hA, Wc + (size_t)g * H_ * C_, bc + (size_t)g * C_,
                logits + (size_t)g * B_ * C_);
        }
    }

    fuse_kernel<<<B_, 64, 0, stream>>>(logits, Wf, bf, out);
}

// Round 8
// 642.364 us; speedup vs baseline: 1.8151x; 1.2522x over previous
//
#include <hip/hip_runtime.h>

// Problem constants (match reference)
#define G_  4
#define N_  100000
#define E_  500000
#define B_  512
#define V_  50000
#define D_  300
#define H_  128
#define C_  20
#define NH_ 3

#define KP_  320   // K padded to 10 x 32 for MFMA
#define SCB_  512                       // elems per scan block
#define NBLK_ ((N_ + SCB_ - 1) / SCB_)  // 196

typedef unsigned short ushort_t;
typedef __attribute__((ext_vector_type(8))) short bf16x8;
typedef __attribute__((ext_vector_type(4))) float f32x4;

__device__ __forceinline__ ushort_t f2bf(float f) {
    unsigned int x = __float_as_uint(f);
    unsigned int r = x + 0x7FFFu + ((x >> 16) & 1u);   // RNE
    return (ushort_t)(r >> 16);
}

__device__ __forceinline__ int lower_bound_i(const int* __restrict__ a, int n, int v) {
    int lo = 0, hi = n;
    while (lo < hi) {
        int mid = (lo + hi) >> 1;
        if (a[mid] < v) lo = mid + 1; else hi = mid;
    }
    return lo;
}

// unpack 8 bf16 (uint4) -> 8 floats
__device__ __forceinline__ void unpack8(uint4 u, float* f) {
    f[0] = __uint_as_float((u.x & 0xFFFFu) << 16);
    f[1] = __uint_as_float(u.x & 0xFFFF0000u);
    f[2] = __uint_as_float((u.y & 0xFFFFu) << 16);
    f[3] = __uint_as_float(u.y & 0xFFFF0000u);
    f[4] = __uint_as_float((u.z & 0xFFFFu) << 16);
    f[5] = __uint_as_float(u.z & 0xFFFF0000u);
    f[6] = __uint_as_float((u.w & 0xFFFFu) << 16);
    f[7] = __uint_as_float(u.w & 0xFFFF0000u);
}

// ---------------------------------------------------------------------------
// Wt[g][n][k] = bf16(Wp[g][k][n]), k zero-padded to KP_=320. One-time, tiny.
// ---------------------------------------------------------------------------
__global__ __launch_bounds__(256) void convert_w_kernel(
    const float* __restrict__ Wp,   // [G][300][128]
    ushort_t* __restrict__ Wt)      // [G][128][KP_]
{
    int flat = blockIdx.x * 256 + threadIdx.x;   // G*128*KP_ = 163840
    int g = flat / (H_ * KP_);
    int r = flat % (H_ * KP_);
    int n = r / KP_;
    int k = r % KP_;
    float v = (k < D_) ? Wp[((size_t)g * D_ + k) * H_ + n] : 0.f;
    Wt[flat] = f2bf(v);
}

// ---------------------------------------------------------------------------
// MFMA projection GEMM: Ph[g][v][h] = bf16( emb[v] @ Wp[g] + bp[g] )
// No LDS: BN=128 = all of N, so A rows have zero cross-block reuse. Each wave
// owns 32x128 output (M_rep=2 x N_rep=8 of 16x16x32 bf16 MFMA). A-fragments
// loaded straight from emb (8 contiguous fp32 -> cvt), B from bf16 Wt (16 B
// contiguous per lane). Fragment layout: lane l -> row/col = l&15,
// k = (l>>4)*8 + j (m97-verified contiguous k-octet); C/D: col=l&15,
// row=(l>>4)*4+reg (m89-verified).
// ---------------------------------------------------------------------------
__global__ __launch_bounds__(256) void mfma_gemm_kernel(
    const float* __restrict__ emb,      // [V][300]
    const ushort_t* __restrict__ Wt,    // [ng][128][KP_] bf16
    const float* __restrict__ bp,       // [ng][128]
    ushort_t* __restrict__ Ph)          // [ng][V][128] bf16
{
    const int g    = blockIdx.x;
    const int row0 = blockIdx.y * 128;
    const int w    = threadIdx.x >> 6;
    const int l    = threadIdx.x & 63;
    const int l16  = l & 15;
    const int lk   = (l >> 4) * 8;   // k-octet base within K-step

    const ushort_t* Wg = Wt + (size_t)g * H_ * KP_;
    ushort_t*       Pg = Ph + (size_t)g * V_ * H_;

    f32x4 acc[2][8];
#pragma unroll
    for (int m = 0; m < 2; ++m)
#pragma unroll
        for (int n = 0; n < 8; ++n) acc[m][n] = (f32x4){0.f, 0.f, 0.f, 0.f};

    const int wrow = row0 + w * 32;
    // clamped rows for the 2 A fragments (stores guarded; clamped loads are
    // finite garbage that is never written)
    int arow[2];
    arow[0] = min(wrow + l16,      V_ - 1);
    arow[1] = min(wrow + 16 + l16, V_ - 1);

    for (int kp0 = 0; kp0 < KP_; kp0 += 32) {
        const int kb = kp0 + lk;

        bf16x8 a[2];
#pragma unroll
        for (int m = 0; m < 2; ++m) {
            float v[8];
            const float* ap = &emb[(size_t)arow[m] * D_ + kb];
            if (kb + 8 <= D_) {
                float4 x0 = *reinterpret_cast<const float4*>(ap);
                float4 x1 = *reinterpret_cast<const float4*>(ap + 4);
                v[0] = x0.x; v[1] = x0.y; v[2] = x0.z; v[3] = x0.w;
                v[4] = x1.x; v[5] = x1.y; v[6] = x1.z; v[7] = x1.w;
            } else {
#pragma unroll
                for (int j = 0; j < 8; ++j)
                    v[j] = (kb + j < D_) ? ap[j] : 0.f;
            }
#pragma unroll
            for (int j = 0; j < 8; ++j) a[m][j] = (short)f2bf(v[j]);
        }

        bf16x8 b[8];
#pragma unroll
        for (int n = 0; n < 8; ++n)
            b[n] = *reinterpret_cast<const bf16x8*>(&Wg[(size_t)(n * 16 + l16) * KP_ + kb]);

#pragma unroll
        for (int m = 0; m < 2; ++m)
#pragma unroll
            for (int n = 0; n < 8; ++n)
                acc[m][n] = __builtin_amdgcn_mfma_f32_16x16x32_bf16(
                    a[m], b[n], acc[m][n], 0, 0, 0);
    }

    // epilogue: bias + bf16 store. row = wrow + m*16 + (l>>4)*4 + r, col = n*16 + l16
    const int rbase = (l >> 4) * 4;
#pragma unroll
    for (int n = 0; n < 8; ++n) {
        const int col  = n * 16 + l16;
        const float bv = bp[g * H_ + col];
#pragma unroll
        for (int m = 0; m < 2; ++m) {
#pragma unroll
            for (int r = 0; r < 4; ++r) {
                int row = wrow + m * 16 + rbase + r;
                if (row < V_)
                    Pg[(size_t)row * H_ + col] = f2bf(acc[m][n][r] + bv);
            }
        }
    }
}

// ---------------------------------------------------------------------------
// Batched CSR build over all G graphs (grid.y = g)
// ---------------------------------------------------------------------------
__global__ __launch_bounds__(256) void deg_count_kernel(const int* __restrict__ dstA,
                                                        int* __restrict__ deg)
{
    const int g = blockIdx.y;
    int e = blockIdx.x * 256 + threadIdx.x;
    if (e < E_) atomicAdd(&deg[g * N_ + dstA[(size_t)g * E_ + e]], 1);
}

__global__ __launch_bounds__(512) void scan1_kernel(const int* __restrict__ deg,
                                                    int* __restrict__ bsum)
{
    __shared__ int sh[512];
    const int g = blockIdx.y, b = blockIdx.x, t = threadIdx.x;
    int i = b * SCB_ + t;
    sh[t] = (i < N_) ? deg[g * N_ + i] : 0;
    __syncthreads();
#pragma unroll
    for (int ofs = 256; ofs > 0; ofs >>= 1) {
        if (t < ofs) sh[t] += sh[t + ofs];
        __syncthreads();
    }
    if (t == 0) bsum[g * NBLK_ + b] = sh[0];
}

__global__ __launch_bounds__(256) void scan2_kernel(const int* __restrict__ bsum,
                                                    int* __restrict__ bpre,
                                                    int* __restrict__ off)
{
    __shared__ int sh[256];
    const int g = blockIdx.x, t = threadIdx.x;
    int v = (t < NBLK_) ? bsum[g * NBLK_ + t] : 0;
    sh[t] = v;
    __syncthreads();
#pragma unroll
    for (int ofs = 1; ofs < 256; ofs <<= 1) {
        int u = (t >= ofs) ? sh[t - ofs] : 0;
        __syncthreads();
        sh[t] += u;
        __syncthreads();
    }
    if (t < NBLK_) bpre[g * (NBLK_ + 1) + t + 1] = sh[t];
    if (t == 0) {
        bpre[g * (NBLK_ + 1)] = 0;
        off[(size_t)g * (N_ + 1) + N_] = sh[NBLK_ - 1];
    }
}

__global__ __launch_bounds__(512) void scan3_kernel(int* __restrict__ deg,
                                                    const int* __restrict__ bpre,
                                                    int* __restrict__ off)
{
    __shared__ int sh[512];
    const int g = blockIdx.y, b = blockIdx.x, t = threadIdx.x;
    int i = b * SCB_ + t;
    int v = (i < N_) ? deg[g * N_ + i] : 0;
    sh[t] = v;
    __syncthreads();
#pragma unroll
    for (int ofs = 1; ofs < 512; ofs <<= 1) {
        int u = (t >= ofs) ? sh[t - ofs] : 0;
        __syncthreads();
        sh[t] += u;
        __syncthreads();
    }
    if (i < N_) {
        off[(size_t)g * (N_ + 1) + i] = bpre[g * (NBLK_ + 1) + b] + sh[t] - v;
        deg[g * N_ + i] = 0;   // becomes cnt for scatter
    }
}

__global__ __launch_bounds__(256) void scatter_kernel(
    const int* __restrict__ srcA, const int* __restrict__ dstA,
    const float* __restrict__ ewA, const float* __restrict__ ep,
    const int* __restrict__ idxA, const int* __restrict__ off,
    int* __restrict__ cnt, int* __restrict__ csr_src,
    int* __restrict__ csr_vsrc, float* __restrict__ csr_coef)
{
    const int g = blockIdx.y;
    int e = blockIdx.x * 256 + threadIdx.x;
    if (e >= E_) return;
    int s = srcA[(size_t)g * E_ + e];
    int d = dstA[(size_t)g * E_ + e];
    int pos = off[(size_t)g * (N_ + 1) + d] + atomicAdd(&cnt[g * N_ + d], 1);
    csr_src[(size_t)g * E_ + pos]  = s;
    csr_vsrc[(size_t)g * E_ + pos] = idxA[(size_t)g * N_ + s];
    float w = ep[g] * ewA[(size_t)g * E_ + e];
    csr_coef[(size_t)g * E_ + pos] = fmaxf(w, 0.f);
}

// ---------------------------------------------------------------------------
// Propagation step 1: hBh[n] = bf16( P[idx[n]] + inv_deg * sum coef * P[vsrc] )
// ---------------------------------------------------------------------------
__global__ __launch_bounds__(256) void prop1_kernel(
    const int* __restrict__ idx_g, const int* __restrict__ off,
    const int* __restrict__ csr_vsrc, const float* __restrict__ csr_coef,
    const ushort_t* __restrict__ Ph, ushort_t* __restrict__ hBh)
{
    const int n = blockIdx.x * 16 + (threadIdx.x >> 4);
    if (n >= N_) return;
    const int lane = threadIdx.x & 15;
    const int col  = lane * 8;

    const int lo = off[n], hi = off[n + 1];

    float sf[8];
    unpack8(*reinterpret_cast<const uint4*>(&Ph[(size_t)idx_g[n] * H_ + col]), sf);

    float acc[8];
#pragma unroll
    for (int j = 0; j < 8; ++j) acc[j] = 0.f;

    int i = lo;
    for (; i + 4 <= hi; i += 4) {
        int   s0 = csr_vsrc[i],     s1 = csr_vsrc[i + 1];
        int   s2 = csr_vsrc[i + 2], s3 = csr_vsrc[i + 3];
        float c0 = csr_coef[i],     c1 = csr_coef[i + 1];
        float c2 = csr_coef[i + 2], c3 = csr_coef[i + 3];
        uint4 u0 = *reinterpret_cast<const uint4*>(&Ph[(size_t)s0 * H_ + col]);
        uint4 u1 = *reinterpret_cast<const uint4*>(&Ph[(size_t)s1 * H_ + col]);
        uint4 u2 = *reinterpret_cast<const uint4*>(&Ph[(size_t)s2 * H_ + col]);
        uint4 u3 = *reinterpret_cast<const uint4*>(&Ph[(size_t)s3 * H_ + col]);
        float f0[8], f1[8], f2[8], f3[8];
        unpack8(u0, f0); unpack8(u1, f1); unpack8(u2, f2); unpack8(u3, f3);
#pragma unroll
        for (int j = 0; j < 8; ++j)
            acc[j] += c0 * f0[j] + c1 * f1[j] + c2 * f2[j] + c3 * f3[j];
    }
    for (; i < hi; ++i) {
        int   s = csr_vsrc[i];
        float c = csr_coef[i];
        float f[8];
        unpack8(*reinterpret_cast<const uint4*>(&Ph[(size_t)s * H_ + col]), f);
#pragma unroll
        for (int j = 0; j < 8; ++j) acc[j] += c * f[j];
    }

    const float inv = (hi > lo) ? 1.0f / (float)(hi - lo) : 0.f;
    ushort_t p[8];
#pragma unroll
    for (int j = 0; j < 8; ++j) p[j] = f2bf(sf[j] + inv * acc[j]);
    uint4 o;
    o.x = (unsigned)p[0] | ((unsigned)p[1] << 16);
    o.y = (unsigned)p[2] | ((unsigned)p[3] << 16);
    o.z = (unsigned)p[4] | ((unsigned)p[5] << 16);
    o.w = (unsigned)p[6] | ((unsigned)p[7] << 16);
    *reinterpret_cast<uint4*>(&hBh[(size_t)n * H_ + col]) = o;
}

// ---------------------------------------------------------------------------
// Propagation step 2: hA[n] = hBh[n] + inv_deg * sum coef * hBh[src]  (fp32 out)
// ---------------------------------------------------------------------------
__global__ __launch_bounds__(256) void prop2_kernel(
    const int* __restrict__ off, const int* __restrict__ csr_src,
    const float* __restrict__ csr_coef,
    const ushort_t* __restrict__ hBh, float* __restrict__ hA)
{
    const int n = blockIdx.x * 16 + (threadIdx.x >> 4);
    if (n >= N_) return;
    const int lane = threadIdx.x & 15;
    const int col  = lane * 8;

    const int lo = off[n], hi = off[n + 1];

    float sf[8];
    unpack8(*reinterpret_cast<const uint4*>(&hBh[(size_t)n * H_ + col]), sf);

    float acc[8];
#pragma unroll
    for (int j = 0; j < 8; ++j) acc[j] = 0.f;

    int i = lo;
    for (; i + 4 <= hi; i += 4) {
        int   s0 = csr_src[i],     s1 = csr_src[i + 1];
        int   s2 = csr_src[i + 2], s3 = csr_src[i + 3];
        float c0 = csr_coef[i],    c1 = csr_coef[i + 1];
        float c2 = csr_coef[i + 2], c3 = csr_coef[i + 3];
        uint4 u0 = *reinterpret_cast<const uint4*>(&hBh[(size_t)s0 * H_ + col]);
        uint4 u1 = *reinterpret_cast<const uint4*>(&hBh[(size_t)s1 * H_ + col]);
        uint4 u2 = *reinterpret_cast<const uint4*>(&hBh[(size_t)s2 * H_ + col]);
        uint4 u3 = *reinterpret_cast<const uint4*>(&hBh[(size_t)s3 * H_ + col]);
        float f0[8], f1[8], f2[8], f3[8];
        unpack8(u0, f0); unpack8(u1, f1); unpack8(u2, f2); unpack8(u3, f3);
#pragma unroll
        for (int j = 0; j < 8; ++j)
            acc[j] += c0 * f0[j] + c1 * f1[j] + c2 * f2[j] + c3 * f3[j];
    }
    for (; i < hi; ++i) {
        int   s = csr_src[i];
        float c = csr_coef[i];
        float f[8];
        unpack8(*reinterpret_cast<const uint4*>(&hBh[(size_t)s * H_ + col]), f);
#pragma unroll
        for (int j = 0; j < 8; ++j) acc[j] += c * f[j];
    }

    const float inv = (hi > lo) ? 1.0f / (float)(hi - lo) : 0.f;
    float4 o0, o1;
    o0.x = sf[0] + inv * acc[0]; o0.y = sf[1] + inv * acc[1];
    o0.z = sf[2] + inv * acc[2]; o0.w = sf[3] + inv * acc[3];
    o1.x = sf[4] + inv * acc[4]; o1.y = sf[5] + inv * acc[5];
    o1.z = sf[6] + inv * acc[6]; o1.w = sf[7] + inv * acc[7];
    *reinterpret_cast<float4*>(&hA[(size_t)n * H_ + col])     = o0;
    *reinterpret_cast<float4*>(&hA[(size_t)n * H_ + col + 4]) = o1;
}

// ---------------------------------------------------------------------------
// Doc pooling + ReLU + classifier. 512 threads/doc: 4 row-quarters x 128 cols
// for 4x the in-flight loads vs 128-thread version (latency-bound loop).
// ---------------------------------------------------------------------------
__global__ __launch_bounds__(512) void doc_cls_kernel(
    const int* __restrict__ gid, const float* __restrict__ h,
    const float* __restrict__ Wc, const float* __restrict__ bc,
    float* __restrict__ logits)
{
    const int b   = blockIdx.x;
    const int tid = threadIdx.x;
    const int col = tid & 127;
    const int q   = tid >> 7;   // 0..3

    int lo = lower_bound_i(gid, N_, b);
    int hi = lower_bound_i(gid, N_, b + 1);

    float s = 0.f;
    for (int n = lo + q; n < hi; n += 4) s += h[(long)n * H_ + col];

    __shared__ float part[4][H_];
    part[q][col] = s;
    __syncthreads();

    __shared__ float sdoc[H_];
    if (tid < H_) {
        float tot = part[0][tid] + part[1][tid] + part[2][tid] + part[3][tid];
        float cnt = (float)(hi - lo);
        sdoc[tid] = fmaxf(tot / fmaxf(cnt, 1.0f), 0.f);
    }
    __syncthreads();

    if (tid < C_) {
        float acc = bc[tid];
#pragma unroll 8
        for (int hh = 0; hh < H_; ++hh) acc += sdoc[hh] * Wc[hh * C_ + tid];
        logits[b * C_ + tid] = acc;
    }
}

// ---------------------------------------------------------------------------
// Head fusion + mean over heads + softmax
// ---------------------------------------------------------------------------
__global__ __launch_bounds__(64) void fuse_kernel(
    const float* __restrict__ logits,  // [G][B][C]
    const float* __restrict__ Wf,      // [NH][C][C][G]
    const float* __restrict__ bf,      // [NH][C]
    float* __restrict__ out)
{
    const int b   = blockIdx.x;
    const int tid = threadIdx.x;

    __shared__ float s[C_ * G_];
    __shared__ float fl[C_];

    for (int t = tid; t < C_ * G_; t += 64) {
        int i = t >> 2, g = t & 3;
        s[t] = logits[((long)g * B_ + b) * C_ + i];
    }
    __syncthreads();

    if (tid < C_) {
        float acc = 0.f;
        for (int hd = 0; hd < NH_; ++hd) {
            float a = bf[hd * C_ + tid];
            const float* wrow = &Wf[((hd * C_ + tid) * C_) * G_];
#pragma unroll 5
            for (int i = 0; i < C_; ++i) {
#pragma unroll
                for (int g = 0; g < G_; ++g)
                    a += s[i * G_ + g] * wrow[i * G_ + g];
            }
            acc += a;
        }
        fl[tid] = acc * (1.0f / 3.0f);
    }
    __syncthreads();

    if (tid < C_) {
        float f = fl[tid];
        float m = -1e30f;
#pragma unroll
        for (int i = 0; i < C_; ++i) m = fmaxf(m, fl[i]);
        float ssum = 0.f;
#pragma unroll
        for (int i = 0; i < C_; ++i) ssum += expf(fl[i] - m);
        out[b * C_ + tid] = expf(f - m) / ssum;
        out[B_ * C_ + b * C_ + tid] = f;
    }
}

// ---------------------------------------------------------------------------
extern "C" void kernel_launch(void* const* d_in, const int* in_sizes, int n_in,
                              void* d_out, int out_size, void* d_ws, size_t ws_size,
                              hipStream_t stream)
{
    const int*   node_indices = (const int*)d_in[0];
    const int*   srcA         = (const int*)d_in[1];
    const int*   dstA         = (const int*)d_in[2];
    const int*   gidA         = (const int*)d_in[3];
    const float* ewA          = (const float*)d_in[4];
    const float* emb          = (const float*)d_in[5];
    const float* ep           = (const float*)d_in[6];
    const float* Wp           = (const float*)d_in[7];
    const float* bp           = (const float*)d_in[8];
    const float* Wc           = (const float*)d_in[9];
    const float* bc           = (const float*)d_in[10];
    const float* Wf           = (const float*)d_in[11];
    const float* bf           = (const float*)d_in[12];
    float*       out          = (float*)d_out;

    // Workspace layout (256B-aligned blocks)
    char* wp0 = (char*)d_ws;
    auto alloc = [&](size_t bytes) {
        void* r = (void*)wp0;
        wp0 += (bytes + 255) & ~(size_t)255;
        return r;
    };
    float*    hA       = (float*)   alloc((size_t)N_ * H_ * 4);   // 51.2 MB
    ushort_t* hBh      = (ushort_t*)alloc((size_t)N_ * H_ * 2);   // 25.6 MB
    float*    logits   = (float*)   alloc((size_t)G_ * B_ * C_ * 4);
    ushort_t* Wt       = (ushort_t*)alloc((size_t)G_ * H_ * KP_ * 2);  // 320 KB
    int*      deg_i    = (int*)     alloc((size_t)G_ * N_ * 4);
    int*      off      = (int*)     alloc((size_t)G_ * (N_ + 1) * 4);
    int*      bsum     = (int*)     alloc((size_t)G_ * NBLK_ * 4);
    int*      bpre     = (int*)     alloc((size_t)G_ * (NBLK_ + 1) * 4);
    int*      csr_src  = (int*)     alloc((size_t)G_ * E_ * 4);
    int*      csr_vsrc = (int*)     alloc((size_t)G_ * E_ * 4);
    float*    csr_coef = (float*)   alloc((size_t)G_ * E_ * 4);

    const size_t pbytes = (size_t)V_ * H_ * 2;   // 12.8 MB per graph (bf16)
    size_t used  = (size_t)(wp0 - (char*)d_ws);
    size_t avail = (ws_size > used) ? ws_size - used : 0;

    int ng;
    ushort_t* Ph;
    if (avail >= 4 * pbytes + 1024) {
        ng = 4; Ph = (ushort_t*)alloc(4 * pbytes);
    } else if (avail >= 2 * pbytes + 1024) {
        ng = 2; Ph = (ushort_t*)alloc(2 * pbytes);
    } else {
        // Alias Ph onto hA (12.8 MB < 51.2 MB). Safe per-graph: Ph consumed by
        // prop1 before prop2 writes hA; GEMM refills Ph next graph.
        ng = 1; Ph = (ushort_t*)hA;
    }

    // ---- one-time weight transpose+convert (tiny) ----
    convert_w_kernel<<<(G_ * H_ * KP_) / 256, 256, 0, stream>>>(Wp, Wt);

    // ---- batched CSR build for all graphs ----
    hipMemsetAsync(deg_i, 0, (size_t)G_ * N_ * sizeof(int), stream);
    deg_count_kernel<<<dim3((E_ + 255) / 256, G_), 256, 0, stream>>>(dstA, deg_i);
    scan1_kernel<<<dim3(NBLK_, G_), 512, 0, stream>>>(deg_i, bsum);
    scan2_kernel<<<G_, 256, 0, stream>>>(bsum, bpre, off);
    scan3_kernel<<<dim3(NBLK_, G_), 512, 0, stream>>>(deg_i, bpre, off);
    scatter_kernel<<<dim3((E_ + 255) / 256, G_), 256, 0, stream>>>(
        srcA, dstA, ewA, ep, node_indices, off, deg_i, csr_src, csr_vsrc, csr_coef);

    // ---- per-graph-group GEMM + per-graph propagation ----
    for (int gbase = 0; gbase < G_; gbase += ng) {
        mfma_gemm_kernel<<<dim3(ng, (V_ + 127) / 128), 256, 0, stream>>>(
            emb, Wt + (size_t)gbase * H_ * KP_, bp + (size_t)gbase * H_, Ph);

        for (int gi = 0; gi < ng; ++gi) {
            const int g = gbase + gi;
            const int*      idx   = node_indices + (size_t)g * N_;
            const int*      gid   = gidA + (size_t)g * N_;
            const int*      off_g = off + (size_t)g * (N_ + 1);
            const ushort_t* Pg    = Ph + (size_t)gi * V_ * H_;

            prop1_kernel<<<(N_ + 15) / 16, 256, 0, stream>>>(
                idx, off_g, csr_vsrc + (size_t)g * E_, csr_coef + (size_t)g * E_,
                Pg, hBh);
            prop2_kernel<<<(N_ + 15) / 16, 256, 0, stream>>>(
                off_g, csr_src + (size_t)g * E_, csr_coef + (size_t)g * E_,
                hBh, hA);

            doc_cls_kernel<<<B_, 512, 0, stream>>>(
                gid, hA, Wc + (size_t)g * H_ * C_, bc + (size_t)g * C_,
                logits + (size_t)g * B_ * C_);
        }
    }

    fuse_kernel<<<B_, 64, 0, stream>>>(logits, Wf, bf, out);
}

// Round 9
// 548.822 us; speedup vs baseline: 2.1244x; 1.1704x over previous
//
#include <hip/hip_runtime.h>

// Problem constants (match reference)
#define G_  4
#define N_  100000
#define E_  500000
#define B_  512
#define V_  50000
#define D_  300
#define H_  128
#define C_  20
#define NH_ 3

#define KP_  320   // K padded to 10 x 32 for MFMA
#define SCB_  512                       // elems per scan block
#define NBLK_ ((N_ + SCB_ - 1) / SCB_)  // 196

typedef unsigned short ushort_t;
typedef __attribute__((ext_vector_type(8))) short bf16x8;
typedef __attribute__((ext_vector_type(4))) float f32x4;

__device__ __forceinline__ ushort_t f2bf(float f) {
    unsigned int x = __float_as_uint(f);
    unsigned int r = x + 0x7FFFu + ((x >> 16) & 1u);   // RNE
    return (ushort_t)(r >> 16);
}

__device__ __forceinline__ int lower_bound_i(const int* __restrict__ a, int n, int v) {
    int lo = 0, hi = n;
    while (lo < hi) {
        int mid = (lo + hi) >> 1;
        if (a[mid] < v) lo = mid + 1; else hi = mid;
    }
    return lo;
}

// unpack 8 bf16 (uint4) -> 8 floats
__device__ __forceinline__ void unpack8(uint4 u, float* f) {
    f[0] = __uint_as_float((u.x & 0xFFFFu) << 16);
    f[1] = __uint_as_float(u.x & 0xFFFF0000u);
    f[2] = __uint_as_float((u.y & 0xFFFFu) << 16);
    f[3] = __uint_as_float(u.y & 0xFFFF0000u);
    f[4] = __uint_as_float((u.z & 0xFFFFu) << 16);
    f[5] = __uint_as_float(u.z & 0xFFFF0000u);
    f[6] = __uint_as_float((u.w & 0xFFFFu) << 16);
    f[7] = __uint_as_float(u.w & 0xFFFF0000u);
}

// ---------------------------------------------------------------------------
// Wt[g][n][k] = bf16(Wp[g][k][n]), k zero-padded to KP_=320. One-time, tiny.
// ---------------------------------------------------------------------------
__global__ __launch_bounds__(256) void convert_w_kernel(
    const float* __restrict__ Wp,   // [G][300][128]
    ushort_t* __restrict__ Wt)      // [G][128][KP_]
{
    int flat = blockIdx.x * 256 + threadIdx.x;   // G*128*KP_ = 163840
    int g = flat / (H_ * KP_);
    int r = flat % (H_ * KP_);
    int n = r / KP_;
    int k = r % KP_;
    float v = (k < D_) ? Wp[((size_t)g * D_ + k) * H_ + n] : 0.f;
    Wt[flat] = f2bf(v);
}

// ---------------------------------------------------------------------------
// MFMA projection GEMM: Ph[g][v][h] = bf16( emb[v] @ Wp[g] + bp[g] )
// No LDS (BN=128 = all of N). Wave owns 32x128 (2x8 fragments, 16x16x32 bf16).
// ---------------------------------------------------------------------------
__global__ __launch_bounds__(256) void mfma_gemm_kernel(
    const float* __restrict__ emb,      // [V][300]
    const ushort_t* __restrict__ Wt,    // [ng][128][KP_] bf16
    const float* __restrict__ bp,       // [ng][128]
    ushort_t* __restrict__ Ph)          // [ng][V][128] bf16
{
    const int g    = blockIdx.x;
    const int row0 = blockIdx.y * 128;
    const int w    = threadIdx.x >> 6;
    const int l    = threadIdx.x & 63;
    const int l16  = l & 15;
    const int lk   = (l >> 4) * 8;   // k-octet base within K-step

    const ushort_t* Wg = Wt + (size_t)g * H_ * KP_;
    ushort_t*       Pg = Ph + (size_t)g * V_ * H_;

    f32x4 acc[2][8];
#pragma unroll
    for (int m = 0; m < 2; ++m)
#pragma unroll
        for (int n = 0; n < 8; ++n) acc[m][n] = (f32x4){0.f, 0.f, 0.f, 0.f};

    const int wrow = row0 + w * 32;
    int arow[2];
    arow[0] = min(wrow + l16,      V_ - 1);
    arow[1] = min(wrow + 16 + l16, V_ - 1);

    for (int kp0 = 0; kp0 < KP_; kp0 += 32) {
        const int kb = kp0 + lk;

        bf16x8 a[2];
#pragma unroll
        for (int m = 0; m < 2; ++m) {
            float v[8];
            const float* ap = &emb[(size_t)arow[m] * D_ + kb];
            if (kb + 8 <= D_) {
                float4 x0 = *reinterpret_cast<const float4*>(ap);
                float4 x1 = *reinterpret_cast<const float4*>(ap + 4);
                v[0] = x0.x; v[1] = x0.y; v[2] = x0.z; v[3] = x0.w;
                v[4] = x1.x; v[5] = x1.y; v[6] = x1.z; v[7] = x1.w;
            } else {
#pragma unroll
                for (int j = 0; j < 8; ++j)
                    v[j] = (kb + j < D_) ? ap[j] : 0.f;
            }
#pragma unroll
            for (int j = 0; j < 8; ++j) a[m][j] = (short)f2bf(v[j]);
        }

        bf16x8 b[8];
#pragma unroll
        for (int n = 0; n < 8; ++n)
            b[n] = *reinterpret_cast<const bf16x8*>(&Wg[(size_t)(n * 16 + l16) * KP_ + kb]);

#pragma unroll
        for (int m = 0; m < 2; ++m)
#pragma unroll
            for (int n = 0; n < 8; ++n)
                acc[m][n] = __builtin_amdgcn_mfma_f32_16x16x32_bf16(
                    a[m], b[n], acc[m][n], 0, 0, 0);
    }

    const int rbase = (l >> 4) * 4;
#pragma unroll
    for (int n = 0; n < 8; ++n) {
        const int col  = n * 16 + l16;
        const float bv = bp[g * H_ + col];
#pragma unroll
        for (int m = 0; m < 2; ++m) {
#pragma unroll
            for (int r = 0; r < 4; ++r) {
                int row = wrow + m * 16 + rbase + r;
                if (row < V_)
                    Pg[(size_t)row * H_ + col] = f2bf(acc[m][n][r] + bv);
            }
        }
    }
}

// ---------------------------------------------------------------------------
// Batched CSR build over all G graphs (grid.y = g)
// ---------------------------------------------------------------------------
__global__ __launch_bounds__(256) void deg_count_kernel(const int* __restrict__ dstA,
                                                        int* __restrict__ deg)
{
    const int g = blockIdx.y;
    int e = blockIdx.x * 256 + threadIdx.x;
    if (e < E_) atomicAdd(&deg[g * N_ + dstA[(size_t)g * E_ + e]], 1);
}

__global__ __launch_bounds__(512) void scan1_kernel(const int* __restrict__ deg,
                                                    int* __restrict__ bsum)
{
    __shared__ int sh[512];
    const int g = blockIdx.y, b = blockIdx.x, t = threadIdx.x;
    int i = b * SCB_ + t;
    sh[t] = (i < N_) ? deg[g * N_ + i] : 0;
    __syncthreads();
#pragma unroll
    for (int ofs = 256; ofs > 0; ofs >>= 1) {
        if (t < ofs) sh[t] += sh[t + ofs];
        __syncthreads();
    }
    if (t == 0) bsum[g * NBLK_ + b] = sh[0];
}

__global__ __launch_bounds__(256) void scan2_kernel(const int* __restrict__ bsum,
                                                    int* __restrict__ bpre,
                                                    int* __restrict__ off)
{
    __shared__ int sh[256];
    const int g = blockIdx.x, t = threadIdx.x;
    int v = (t < NBLK_) ? bsum[g * NBLK_ + t] : 0;
    sh[t] = v;
    __syncthreads();
#pragma unroll
    for (int ofs = 1; ofs < 256; ofs <<= 1) {
        int u = (t >= ofs) ? sh[t - ofs] : 0;
        __syncthreads();
        sh[t] += u;
        __syncthreads();
    }
    if (t < NBLK_) bpre[g * (NBLK_ + 1) + t + 1] = sh[t];
    if (t == 0) {
        bpre[g * (NBLK_ + 1)] = 0;
        off[(size_t)g * (N_ + 1) + N_] = sh[NBLK_ - 1];
    }
}

__global__ __launch_bounds__(512) void scan3_kernel(int* __restrict__ deg,
                                                    const int* __restrict__ bpre,
                                                    int* __restrict__ off)
{
    __shared__ int sh[512];
    const int g = blockIdx.y, b = blockIdx.x, t = threadIdx.x;
    int i = b * SCB_ + t;
    int v = (i < N_) ? deg[g * N_ + i] : 0;
    sh[t] = v;
    __syncthreads();
#pragma unroll
    for (int ofs = 1; ofs < 512; ofs <<= 1) {
        int u = (t >= ofs) ? sh[t - ofs] : 0;
        __syncthreads();
        sh[t] += u;
        __syncthreads();
    }
    if (i < N_) {
        off[(size_t)g * (N_ + 1) + i] = bpre[g * (NBLK_ + 1) + b] + sh[t] - v;
        deg[g * N_ + i] = 0;   // becomes cnt for scatter
    }
}

// ---------------------------------------------------------------------------
// Scatter: single int4 payload {src, vsrc, coef_bits, 0} -> ONE random
// cache-line touch per edge (was 3 separate 4B stores = 3 line touches).
// ---------------------------------------------------------------------------
__global__ __launch_bounds__(256) void scatter_kernel(
    const int* __restrict__ srcA, const int* __restrict__ dstA,
    const float* __restrict__ ewA, const float* __restrict__ ep,
    const int* __restrict__ idxA, const int* __restrict__ off,
    int* __restrict__ cnt, int4* __restrict__ csr4)
{
    const int g = blockIdx.y;
    int e = blockIdx.x * 256 + threadIdx.x;
    if (e >= E_) return;
    int s = srcA[(size_t)g * E_ + e];
    int d = dstA[(size_t)g * E_ + e];
    int pos = off[(size_t)g * (N_ + 1) + d] + atomicAdd(&cnt[g * N_ + d], 1);
    float w = ep[g] * ewA[(size_t)g * E_ + e];
    csr4[(size_t)g * E_ + pos] =
        make_int4(s, idxA[(size_t)g * N_ + s], __float_as_int(fmaxf(w, 0.f)), 0);
}

// ---------------------------------------------------------------------------
// Propagation step 1: hBh[n] = bf16( P[idx[n]] + inv_deg * sum coef * P[vsrc] )
// 16 lanes/node (ushort8 = 16 B per lane); 16 nodes/block; 4-deep unroll.
// ---------------------------------------------------------------------------
__global__ __launch_bounds__(256) void prop1_kernel(
    const int* __restrict__ idx_g, const int* __restrict__ off,
    const int4* __restrict__ csr4,
    const ushort_t* __restrict__ Ph, ushort_t* __restrict__ hBh)
{
    const int n = blockIdx.x * 16 + (threadIdx.x >> 4);
    if (n >= N_) return;
    const int lane = threadIdx.x & 15;
    const int col  = lane * 8;

    const int lo = off[n], hi = off[n + 1];

    float sf[8];
    unpack8(*reinterpret_cast<const uint4*>(&Ph[(size_t)idx_g[n] * H_ + col]), sf);

    float acc[8];
#pragma unroll
    for (int j = 0; j < 8; ++j) acc[j] = 0.f;

    int i = lo;
    for (; i + 4 <= hi; i += 4) {
        int4 e0 = csr4[i],     e1 = csr4[i + 1];
        int4 e2 = csr4[i + 2], e3 = csr4[i + 3];
        float c0 = __int_as_float(e0.z), c1 = __int_as_float(e1.z);
        float c2 = __int_as_float(e2.z), c3 = __int_as_float(e3.z);
        uint4 u0 = *reinterpret_cast<const uint4*>(&Ph[(size_t)e0.y * H_ + col]);
        uint4 u1 = *reinterpret_cast<const uint4*>(&Ph[(size_t)e1.y * H_ + col]);
        uint4 u2 = *reinterpret_cast<const uint4*>(&Ph[(size_t)e2.y * H_ + col]);
        uint4 u3 = *reinterpret_cast<const uint4*>(&Ph[(size_t)e3.y * H_ + col]);
        float f0[8], f1[8], f2[8], f3[8];
        unpack8(u0, f0); unpack8(u1, f1); unpack8(u2, f2); unpack8(u3, f3);
#pragma unroll
        for (int j = 0; j < 8; ++j)
            acc[j] += c0 * f0[j] + c1 * f1[j] + c2 * f2[j] + c3 * f3[j];
    }
    for (; i < hi; ++i) {
        int4 e0 = csr4[i];
        float c = __int_as_float(e0.z);
        float f[8];
        unpack8(*reinterpret_cast<const uint4*>(&Ph[(size_t)e0.y * H_ + col]), f);
#pragma unroll
        for (int j = 0; j < 8; ++j) acc[j] += c * f[j];
    }

    const float inv = (hi > lo) ? 1.0f / (float)(hi - lo) : 0.f;
    ushort_t p[8];
#pragma unroll
    for (int j = 0; j < 8; ++j) p[j] = f2bf(sf[j] + inv * acc[j]);
    uint4 o;
    o.x = (unsigned)p[0] | ((unsigned)p[1] << 16);
    o.y = (unsigned)p[2] | ((unsigned)p[3] << 16);
    o.z = (unsigned)p[4] | ((unsigned)p[5] << 16);
    o.w = (unsigned)p[6] | ((unsigned)p[7] << 16);
    *reinterpret_cast<uint4*>(&hBh[(size_t)n * H_ + col]) = o;
}

// ---------------------------------------------------------------------------
// Propagation step 2 + fused doc pooling:
//   o[n] = hBh[n] + inv_deg * sum coef * hBh[src]   (never materialized)
//   docsum[gid[n]] += o[n]   via run-segmented LDS reduction (gid is SORTED:
//   each 16-node block spans <=2-3 docs -> few atomics, at segment boundaries)
// ---------------------------------------------------------------------------
__global__ __launch_bounds__(256) void prop2_fused_kernel(
    const int* __restrict__ off, const int4* __restrict__ csr4,
    const int* __restrict__ gid,
    const ushort_t* __restrict__ hBh, float* __restrict__ docsum)
{
    const int nloc = threadIdx.x >> 4;          // 0..15
    const int n    = blockIdx.x * 16 + nloc;
    const int lane = threadIdx.x & 15;
    const int col  = lane * 8;

    __shared__ float sh[16][H_];
    __shared__ int   shgid[16];

    float o[8];
    if (n < N_) {
        const int lo = off[n], hi = off[n + 1];

        float sf[8];
        unpack8(*reinterpret_cast<const uint4*>(&hBh[(size_t)n * H_ + col]), sf);

        float acc[8];
#pragma unroll
        for (int j = 0; j < 8; ++j) acc[j] = 0.f;

        int i = lo;
        for (; i + 4 <= hi; i += 4) {
            int4 e0 = csr4[i],     e1 = csr4[i + 1];
            int4 e2 = csr4[i + 2], e3 = csr4[i + 3];
            float c0 = __int_as_float(e0.z), c1 = __int_as_float(e1.z);
            float c2 = __int_as_float(e2.z), c3 = __int_as_float(e3.z);
            uint4 u0 = *reinterpret_cast<const uint4*>(&hBh[(size_t)e0.x * H_ + col]);
            uint4 u1 = *reinterpret_cast<const uint4*>(&hBh[(size_t)e1.x * H_ + col]);
            uint4 u2 = *reinterpret_cast<const uint4*>(&hBh[(size_t)e2.x * H_ + col]);
            uint4 u3 = *reinterpret_cast<const uint4*>(&hBh[(size_t)e3.x * H_ + col]);
            float f0[8], f1[8], f2[8], f3[8];
            unpack8(u0, f0); unpack8(u1, f1); unpack8(u2, f2); unpack8(u3, f3);
#pragma unroll
            for (int j = 0; j < 8; ++j)
                acc[j] += c0 * f0[j] + c1 * f1[j] + c2 * f2[j] + c3 * f3[j];
        }
        for (; i < hi; ++i) {
            int4 e0 = csr4[i];
            float c = __int_as_float(e0.z);
            float f[8];
            unpack8(*reinterpret_cast<const uint4*>(&hBh[(size_t)e0.x * H_ + col]), f);
#pragma unroll
            for (int j = 0; j < 8; ++j) acc[j] += c * f[j];
        }

        const float inv = (hi > lo) ? 1.0f / (float)(hi - lo) : 0.f;
#pragma unroll
        for (int j = 0; j < 8; ++j) o[j] = sf[j] + inv * acc[j];
        if (lane == 0) shgid[nloc] = gid[n];
    } else {
#pragma unroll
        for (int j = 0; j < 8; ++j) o[j] = 0.f;
        if (lane == 0) shgid[nloc] = -1;
    }

#pragma unroll
    for (int j = 0; j < 8; ++j) sh[nloc][col + j] = o[j];
    __syncthreads();

    // run-segmented column sums: 2 halves x 128 cols; 8 nodes per half
    const int c  = threadIdx.x & 127;
    const int q  = threadIdx.x >> 7;      // 0/1
    const int n0 = q * 8;
    float run = 0.f;
    int rgid = shgid[n0];
    for (int k = 0; k < 8; ++k) {
        int gk = shgid[n0 + k];
        if (gk != rgid) {
            if (rgid >= 0) atomicAdd(&docsum[(size_t)rgid * H_ + c], run);
            run = 0.f; rgid = gk;
        }
        run += sh[n0 + k][c];
    }
    if (rgid >= 0) atomicAdd(&docsum[(size_t)rgid * H_ + c], run);
}

// ---------------------------------------------------------------------------
// Classifier from docsum: logits[g][b][:] = relu(docsum/cnt) @ Wc + bc
// ---------------------------------------------------------------------------
__global__ __launch_bounds__(128) void cls_kernel(
    const int* __restrict__ gidA, const float* __restrict__ docsum,
    const float* __restrict__ Wc, const float* __restrict__ bc,
    float* __restrict__ logits)
{
    const int b   = blockIdx.x;
    const int g   = blockIdx.y;
    const int tid = threadIdx.x;
    const int* gid = gidA + (size_t)g * N_;

    int lo = lower_bound_i(gid, N_, b);
    int hi = lower_bound_i(gid, N_, b + 1);
    float cnt = (float)(hi - lo);

    __shared__ float sdoc[H_];
    float dv = docsum[((size_t)g * B_ + b) * H_ + tid] / fmaxf(cnt, 1.0f);
    sdoc[tid] = fmaxf(dv, 0.f);
    __syncthreads();

    if (tid < C_) {
        const float* Wcg = Wc + (size_t)g * H_ * C_;
        float acc = bc[g * C_ + tid];
#pragma unroll 8
        for (int hh = 0; hh < H_; ++hh) acc += sdoc[hh] * Wcg[hh * C_ + tid];
        logits[((size_t)g * B_ + b) * C_ + tid] = acc;
    }
}

// ---------------------------------------------------------------------------
// Head fusion + mean over heads + softmax
// ---------------------------------------------------------------------------
__global__ __launch_bounds__(64) void fuse_kernel(
    const float* __restrict__ logits,  // [G][B][C]
    const float* __restrict__ Wf,      // [NH][C][C][G]
    const float* __restrict__ bf,      // [NH][C]
    float* __restrict__ out)
{
    const int b   = blockIdx.x;
    const int tid = threadIdx.x;

    __shared__ float s[C_ * G_];
    __shared__ float fl[C_];

    for (int t = tid; t < C_ * G_; t += 64) {
        int i = t >> 2, g = t & 3;
        s[t] = logits[((long)g * B_ + b) * C_ + i];
    }
    __syncthreads();

    if (tid < C_) {
        float acc = 0.f;
        for (int hd = 0; hd < NH_; ++hd) {
            float a = bf[hd * C_ + tid];
            const float* wrow = &Wf[((hd * C_ + tid) * C_) * G_];
#pragma unroll 5
        for (int i = 0; i < C_; ++i) {
#pragma unroll
                for (int g = 0; g < G_; ++g)
                    a += s[i * G_ + g] * wrow[i * G_ + g];
            }
            acc += a;
        }
        fl[tid] = acc * (1.0f / 3.0f);
    }
    __syncthreads();

    if (tid < C_) {
        float f = fl[tid];
        float m = -1e30f;
#pragma unroll
        for (int i = 0; i < C_; ++i) m = fmaxf(m, fl[i]);
        float ssum = 0.f;
#pragma unroll
        for (int i = 0; i < C_; ++i) ssum += expf(fl[i] - m);
        out[b * C_ + tid] = expf(f - m) / ssum;
        out[B_ * C_ + b * C_ + tid] = f;
    }
}

// ---------------------------------------------------------------------------
extern "C" void kernel_launch(void* const* d_in, const int* in_sizes, int n_in,
                              void* d_out, int out_size, void* d_ws, size_t ws_size,
                              hipStream_t stream)
{
    const int*   node_indices = (const int*)d_in[0];
    const int*   srcA         = (const int*)d_in[1];
    const int*   dstA         = (const int*)d_in[2];
    const int*   gidA         = (const int*)d_in[3];
    const float* ewA          = (const float*)d_in[4];
    const float* emb          = (const float*)d_in[5];
    const float* ep           = (const float*)d_in[6];
    const float* Wp           = (const float*)d_in[7];
    const float* bp           = (const float*)d_in[8];
    const float* Wc           = (const float*)d_in[9];
    const float* bc           = (const float*)d_in[10];
    const float* Wf           = (const float*)d_in[11];
    const float* bf           = (const float*)d_in[12];
    float*       out          = (float*)d_out;

    // Workspace layout (256B-aligned blocks)
    char* wp0 = (char*)d_ws;
    auto alloc = [&](size_t bytes) {
        void* r = (void*)wp0;
        wp0 += (bytes + 255) & ~(size_t)255;
        return r;
    };
    ushort_t* hBh      = (ushort_t*)alloc((size_t)N_ * H_ * 2);          // 25.6 MB
    float*    docsum   = (float*)   alloc((size_t)G_ * B_ * H_ * 4);     // 1 MB
    float*    logits   = (float*)   alloc((size_t)G_ * B_ * C_ * 4);
    ushort_t* Wt       = (ushort_t*)alloc((size_t)G_ * H_ * KP_ * 2);    // 320 KB
    int*      deg_i    = (int*)     alloc((size_t)G_ * N_ * 4);
    int*      off      = (int*)     alloc((size_t)G_ * (N_ + 1) * 4);
    int*      bsum     = (int*)     alloc((size_t)G_ * NBLK_ * 4);
    int*      bpre     = (int*)     alloc((size_t)G_ * (NBLK_ + 1) * 4);
    int4*     csr4     = (int4*)    alloc((size_t)G_ * E_ * 16);         // 32 MB

    const size_t pbytes = (size_t)V_ * H_ * 2;   // 12.8 MB per graph (bf16)
    size_t used  = (size_t)(wp0 - (char*)d_ws);
    size_t avail = (ws_size > used) ? ws_size - used : 0;

    int ng;
    if (avail >= 4 * pbytes + 1024)      ng = 4;
    else if (avail >= 2 * pbytes + 1024) ng = 2;
    else                                 ng = 1;
    ushort_t* Ph = (ushort_t*)alloc((size_t)ng * pbytes);

    // ---- one-time weight transpose+convert + zero docsum ----
    convert_w_kernel<<<(G_ * H_ * KP_) / 256, 256, 0, stream>>>(Wp, Wt);
    hipMemsetAsync(docsum, 0, (size_t)G_ * B_ * H_ * sizeof(float), stream);

    // ---- batched CSR build for all graphs ----
    hipMemsetAsync(deg_i, 0, (size_t)G_ * N_ * sizeof(int), stream);
    deg_count_kernel<<<dim3((E_ + 255) / 256, G_), 256, 0, stream>>>(dstA, deg_i);
    scan1_kernel<<<dim3(NBLK_, G_), 512, 0, stream>>>(deg_i, bsum);
    scan2_kernel<<<G_, 256, 0, stream>>>(bsum, bpre, off);
    scan3_kernel<<<dim3(NBLK_, G_), 512, 0, stream>>>(deg_i, bpre, off);
    scatter_kernel<<<dim3((E_ + 255) / 256, G_), 256, 0, stream>>>(
        srcA, dstA, ewA, ep, node_indices, off, deg_i, csr4);

    // ---- per-graph-group GEMM + per-graph propagation ----
    for (int gbase = 0; gbase < G_; gbase += ng) {
        mfma_gemm_kernel<<<dim3(ng, (V_ + 127) / 128), 256, 0, stream>>>(
            emb, Wt + (size_t)gbase * H_ * KP_, bp + (size_t)gbase * H_, Ph);

        for (int gi = 0; gi < ng; ++gi) {
            const int g = gbase + gi;
            const int*      idx   = node_indices + (size_t)g * N_;
            const int*      gid   = gidA + (size_t)g * N_;
            const int*      off_g = off + (size_t)g * (N_ + 1);
            const int4*     csr_g = csr4 + (size_t)g * E_;
            const ushort_t* Pg    = Ph + (size_t)gi * V_ * H_;

            prop1_kernel<<<(N_ + 15) / 16, 256, 0, stream>>>(
                idx, off_g, csr_g, Pg, hBh);
            prop2_fused_kernel<<<(N_ + 15) / 16, 256, 0, stream>>>(
                off_g, csr_g, gid, hBh, docsum + (size_t)g * B_ * H_);
        }
    }

    cls_kernel<<<dim3(B_, G_), 128, 0, stream>>>(gidA, docsum, Wc, bc, logits);
    fuse_kernel<<<B_, 64, 0, stream>>>(logits, Wf, bf, out);
}